// Round 1
// baseline (4386.009 us; speedup 1.0000x reference)
//
#include <hip/hip_runtime.h>

#define NEG_SLOPE 0.2f

// ---------------------------------------------------------------- build A ---
__global__ __launch_bounds__(256) void kA_build(const int* __restrict__ ei,
                                                float* __restrict__ A, int E)
{
    int e = blockIdx.x * 256 + threadIdx.x;
    if (e >= E) return;
    int s = ei[e], d = ei[E + e];
    int g = s >> 7;                       // 128 nodes per group
    atomicAdd(&A[((g * 128 + (s & 127)) * 128) + (d & 127)], 1.0f);
}

// ------------------------------------------------- graph_conv + relu + gpool
// one block per group. agg = (A^T h)/deg staged in LDS, then two fused GEMVs.
__global__ __launch_bounds__(512) void k_conv(
    const float* __restrict__ h_in, const float* __restrict__ Ab,
    const float* __restrict__ wrel, const float* __restrict__ brel,
    const float* __restrict__ wroot,
    float* __restrict__ h_out, float* __restrict__ gp,
    int n, int Cin, int Cout)
{
    const int g = blockIdx.x;
    const float* A  = Ab   + (size_t)g * n * n;
    const float* hi = h_in + (size_t)g * n * Cin;
    float* ho = h_out + (size_t)g * n * Cout;
    __shared__ __align__(16) float agg[128 * 128];
    __shared__ float sdeg[128];
    const int tid = threadIdx.x;
    const int B = blockDim.x;

    // deg[j] = max(nnz(col j), 1)
    for (int j = tid; j < n; j += B) {
        int cnt = 0;
        for (int i = 0; i < n; ++i) cnt += (A[i * n + j] != 0.0f) ? 1 : 0;
        sdeg[j] = fmaxf((float)cnt, 1.0f);
    }
    __syncthreads();

    // agg[j][c] = sum_i A[i][j] h[i][c] / deg[j]   (true division, matches ref)
    const int q4 = Cin >> 2;
    for (int idx = tid; idx < n * q4; idx += B) {
        int j = idx / q4, c4 = idx - j * q4;
        float sx = 0.f, sy = 0.f, sz = 0.f, sw = 0.f;
        for (int i = 0; i < n; ++i) {
            float a = A[i * n + j];
            if (a != 0.0f) {               // wave-uniform skip (exact: a==0 adds 0)
                float4 hv = *(const float4*)(hi + i * Cin + (c4 << 2));
                sx += a * hv.x; sy += a * hv.y; sz += a * hv.z; sw += a * hv.w;
            }
        }
        float d = sdeg[j];
        float4 o; o.x = sx / d; o.y = sy / d; o.z = sz / d; o.w = sw / d;
        *(float4*)(agg + j * Cin + (c4 << 2)) = o;
    }
    __syncthreads();

    // out[j][c2] = relu(agg[j]·wrel[c2] + brel[c2] + h[j]·wroot[c2])
    for (int idx = tid; idx < n * Cout; idx += B) {
        int j = idx / Cout, c2 = idx - j * Cout;
        const float4* wr = (const float4*)(wrel  + c2 * Cin);
        const float4* wo = (const float4*)(wroot + c2 * Cin);
        const float4* ag = (const float4*)(agg + j * Cin);
        const float4* hj = (const float4*)(hi  + j * Cin);
        float acc = 0.f;
        for (int c4 = 0; c4 < q4; ++c4) {
            float4 a = ag[c4], w1 = wr[c4];
            acc += a.x*w1.x + a.y*w1.y + a.z*w1.z + a.w*w1.w;
            float4 h4 = hj[c4], w2 = wo[c4];
            acc += h4.x*w2.x + h4.y*w2.y + h4.z*w2.z + h4.w*w2.w;
        }
        ho[idx] = fmaxf(acc + brel[c2], 0.0f);
    }
    __syncthreads();

    // fused gpool: mean over the group's rows
    for (int c = tid; c < Cout; c += B) {
        float s = 0.f;
        for (int i = 0; i < n; ++i) s += ho[i * Cout + c];
        gp[g * Cout + c] = s / (float)n;
    }
}

// ------------------------------------------------------------- ASAP pooling
// one block per group. C = 128 fixed.
__global__ __launch_bounds__(512) void k_pool(
    const float* __restrict__ h_in, const float* __restrict__ A_in,
    float* __restrict__ h_out, float* __restrict__ A_out,
    float* __restrict__ xn_ws, float* __restrict__ T_ws,
    const float* __restrict__ lin_w, const float* __restrict__ lin_b,
    const float* __restrict__ att_w, const float* __restrict__ att_bp,
    const float* __restrict__ le1_w, const float* __restrict__ le1_bp,
    const float* __restrict__ le2_w, const float* __restrict__ le3_w,
    const float* __restrict__ le3_bp,
    int n, int k)
{
    const int C = 128;
    const int g = blockIdx.x;
    const float* hg = h_in + (size_t)g * n * C;
    const float* Ag = A_in + (size_t)g * n * n;
    float* hog = h_out + (size_t)g * k * C;
    float* Aog = A_out + (size_t)g * k * k;
    float* xng = xn_ws + (size_t)g * n * C;
    float* Tg  = T_ws  + (size_t)g * n * k;

    __shared__ __align__(16) float h_s[128 * 128];   // 64 KB
    __shared__ float S_s[128 * 129];                 // 64.5 KB, column-major, odd stride
    __shared__ unsigned int Mb[128 * 4];             // column bitmasks (incl. diagonal)
    __shared__ float v_s[128], qa_s[128], xa_s[128], deg_s[128], fit_s[128];
    __shared__ float a_s[128], b_s[128], c3_s[128];
    __shared__ int perm_s[128];
    __shared__ float c0_s;

    const int tid = threadIdx.x;
    const int B = blockDim.x;
    const int lane = tid & 63;
    const int wid = tid >> 6;
    const int nw = B >> 6;
    const int sstride = (n & 1) ? n : (n + 1);
    const float att_b = att_bp[0];

    // load h tile
    for (int idx = tid; idx < n * C; idx += B) h_s[idx] = hg[idx];

    // v = lin_w^T a_q ; c0 = lin_b·a_q  (collapses q@a_q to mcm·v + c0)
    for (int c = tid; c < C; c += B) {
        float s = 0.f;
        for (int c2 = 0; c2 < C; ++c2) s += att_w[c2] * lin_w[c2 * C + c];
        v_s[c] = s;
    }
    if (tid == 0) {
        float s = 0.f;
        for (int c2 = 0; c2 < C; ++c2) s += att_w[c2] * lin_b[c2];
        c0_s = s;
    }
    // column bitmasks of M = (A_d != 0), A_d = A with unit diagonal; deg = popcount
    for (int j = tid; j < n; j += B) {
        int cnt = 0;
        for (int w = 0; w < 4; ++w) {
            unsigned int word = 0u;
            int base = w << 5;
            for (int b = 0; b < 32; ++b) {
                int i = base + b;
                if (i < n && (i == j || Ag[i * n + j] != 0.0f)) word |= (1u << b);
            }
            Mb[j * 4 + w] = word;
            cnt += __popc(word);
        }
        deg_s[j] = (float)cnt;
    }
    __syncthreads();

    // qa[j] = (masked col-max of h over in-nbrs of j)·v + c0   (wave per column)
    for (int j = wid; j < n; j += nw) {
        float acc = 0.f;
        for (int half = 0; half < C; half += 64) {
            const int c = lane + half;
            float m = -1e30f;
            for (int w = 0; w < 4; ++w) {
                unsigned int word = Mb[j * 4 + w];       // wave-uniform
                while (word) {
                    int i = (w << 5) + __ffs(word) - 1;
                    word &= word - 1u;
                    m = fmaxf(m, h_s[i * C + c]);
                }
            }
            acc += m * v_s[c];
        }
        for (int off = 32; off; off >>= 1) acc += __shfl_xor(acc, off);
        if (lane == 0) qa_s[j] = acc + c0_s;
    }
    // xa[i] = h[i]·a_x   (wave per row)
    for (int i = wid; i < n; i += nw) {
        float s = h_s[i * C + lane] * att_w[C + lane]
                + h_s[i * C + 64 + lane] * att_w[C + 64 + lane];
        for (int off = 32; off; off >>= 1) s += __shfl_xor(s, off);
        if (lane == 0) xa_s[i] = s;
    }
    __syncthreads();

    // S column softmax over masked rows (wave per column; lanes cover i, i+64)
    for (int j = wid; j < n; j += nw) {
        const float qaj = qa_s[j];
        const int i0 = lane, i1 = lane + 64;
        const bool b0 = (i0 < n) && ((Mb[j * 4 + (i0 >> 5)] >> (i0 & 31)) & 1u);
        const bool b1 = (i1 < n) && ((Mb[j * 4 + (i1 >> 5)] >> (i1 & 31)) & 1u);
        float l0 = -1e30f, l1 = -1e30f;
        if (b0) { float t = xa_s[i0] + qaj + att_b; l0 = (t >= 0.f) ? t : NEG_SLOPE * t; }
        if (b1) { float t = xa_s[i1] + qaj + att_b; l1 = (t >= 0.f) ? t : NEG_SLOPE * t; }
        float m = fmaxf(l0, l1);
        for (int off = 32; off; off >>= 1) m = fmaxf(m, __shfl_xor(m, off));
        float e0 = b0 ? expf(l0 - m) : 0.f;
        float e1 = b1 ? expf(l1 - m) : 0.f;
        float s = e0 + e1;
        for (int off = 32; off; off >>= 1) s += __shfl_xor(s, off);
        if (i0 < n) S_s[j * sstride + i0] = e0 / s;
        if (i1 < n) S_s[j * sstride + i1] = e1 / s;
    }
    __syncthreads();

    // x_new = S^T h  -> global scratch
    for (int idx = tid; idx < n * 32; idx += B) {        // 32 = C/4
        int j = idx >> 5, c4 = idx & 31;
        const float* Sj = S_s + j * sstride;
        float sx = 0.f, sy = 0.f, sz = 0.f, sw = 0.f;
        for (int i = 0; i < n; ++i) {
            float sv = Sj[i];
            if (sv != 0.0f) {
                float4 hv = *(const float4*)(h_s + i * C + (c4 << 2));
                sx += sv*hv.x; sy += sv*hv.y; sz += sv*hv.z; sw += sv*hv.w;
            }
        }
        float4 o; o.x = sx; o.y = sy; o.z = sz; o.w = sw;
        *(float4*)(xng + j * C + (c4 << 2)) = o;
    }
    __syncthreads();

    // a = x_new·le1 + b1 ; b = x_new·le2 ; c3 = x_new·le3   (wave per row)
    for (int j = wid; j < n; j += nw) {
        float x0 = xng[j * C + lane], x1 = xng[j * C + 64 + lane];
        float s1 = x0 * le1_w[lane] + x1 * le1_w[64 + lane];
        float s2 = x0 * le2_w[lane] + x1 * le2_w[64 + lane];
        float s3 = x0 * le3_w[lane] + x1 * le3_w[64 + lane];
        for (int off = 32; off; off >>= 1) {
            s1 += __shfl_xor(s1, off);
            s2 += __shfl_xor(s2, off);
            s3 += __shfl_xor(s3, off);
        }
        if (lane == 0) { a_s[j] = s1 + le1_bp[0]; b_s[j] = s2; c3_s[j] = s3; }
    }
    __syncthreads();

    // fitness[j] = sigmoid( sum_{i in col j} a[i] - deg[j] b[j] + c3[j] + le3_b )
    for (int j = tid; j < n; j += B) {
        float s = 0.f;
        for (int w = 0; w < 4; ++w) {
            unsigned int word = Mb[j * 4 + w];
            while (word) {
                int i = (w << 5) + __ffs(word) - 1;
                word &= word - 1u;
                s += a_s[i];
            }
        }
        float f = s - deg_s[j] * b_s[j] + c3_s[j] + le3_bp[0];
        fit_s[j] = 1.0f / (1.0f + expf(-f));
    }
    __syncthreads();

    // top-k via rank = #{j2 : f2>fj or (f2==fj and j2<j)}  (matches lax.top_k order)
    for (int j = tid; j < n; j += B) {
        float fj = fit_s[j];
        int r = 0;
        for (int j2 = 0; j2 < n; ++j2) {
            float f2 = fit_s[j2];
            if (f2 > fj || (f2 == fj && j2 < j)) ++r;
        }
        if (r < k) perm_s[r] = j;
    }
    __syncthreads();

    // h_out[r] = x_new[perm[r]] * fitness[perm[r]]
    for (int idx = tid; idx < k * C; idx += B) {
        int r = idx >> 7, c = idx & 127;
        int p = perm_s[r];
        hog[idx] = xng[p * C + c] * fit_s[p];
    }
    // T = A_d @ S_sel
    for (int idx = tid; idx < n * k; idx += B) {
        int i = idx / k, cc = idx - i * k;
        const float* Sp = S_s + perm_s[cc] * sstride;
        const float* Ai = Ag + i * n;
        float s = 0.f;
        for (int j = 0; j < n; ++j) {
            float av = (j == i) ? 1.0f : Ai[j];
            if (av != 0.0f) s += av * Sp[j];
        }
        Tg[idx] = s;
    }
    __syncthreads();
    // A2 = S_sel^T @ T, unit diagonal
    for (int idx = tid; idx < k * k; idx += B) {
        int r = idx / k, cc = idx - r * k;
        const float* Sr = S_s + perm_s[r] * sstride;
        float s = 0.f;
        for (int i = 0; i < n; ++i) {
            float sv = Sr[i];
            if (sv != 0.0f) s += sv * Tg[i * k + cc];
        }
        Aog[idx] = (r == cc) ? 1.0f : s;
    }
}

// ------------------------------------------------------------- classifier ---
__global__ __launch_bounds__(256) void k_final(
    const float* __restrict__ xs,     // [5][16][128]
    const float* __restrict__ w1, const float* __restrict__ b1,
    const float* __restrict__ w2, const float* __restrict__ b2,
    float* __restrict__ out)
{
    __shared__ float z1[16 * 128];
    const int tid = threadIdx.x;
    for (int idx = tid; idx < 2048; idx += blockDim.x) {
        int g = idx >> 7, c2 = idx & 127;
        const float* wrow = w1 + c2 * 640;
        float s = b1[c2];
        for (int t = 0; t < 5; ++t) {
            const float4* xv = (const float4*)(xs + t * 2048 + g * 128);
            const float4* wv = (const float4*)(wrow + t * 128);
            for (int c4 = 0; c4 < 32; ++c4) {
                float4 a = xv[c4], b = wv[c4];
                s += a.x*b.x + a.y*b.y + a.z*b.z + a.w*b.w;
            }
        }
        z1[idx] = fmaxf(s, 0.0f);
    }
    __syncthreads();
    if (tid < 16) {
        float za = b2[0], zb = b2[1];
        for (int c = 0; c < 128; ++c) {
            float zv = z1[tid * 128 + c];
            za += zv * w2[c];
            zb += zv * w2[128 + c];
        }
        float m = fmaxf(za, zb);
        float lse = m + logf(expf(za - m) + expf(zb - m));
        out[tid * 2 + 0] = za - lse;
        out[tid * 2 + 1] = zb - lse;
    }
}

// ---------------------------------------------------------------------------
extern "C" void kernel_launch(void* const* d_in, const int* in_sizes, int n_in,
                              void* d_out, int out_size, void* d_ws, size_t ws_size,
                              hipStream_t stream)
{
    (void)n_in; (void)out_size; (void)ws_size;
    const float* x        = (const float*)d_in[0];
    const int*   ei       = (const int*)  d_in[1];
    const float* c0_wrel  = (const float*)d_in[2];
    const float* c0_brel  = (const float*)d_in[3];
    const float* c0_wroot = (const float*)d_in[4];
    const float* cw_rel   = (const float*)d_in[5];
    const float* cb_rel   = (const float*)d_in[6];
    const float* cw_root  = (const float*)d_in[7];
    const float* p_lin_w  = (const float*)d_in[8];
    const float* p_lin_b  = (const float*)d_in[9];
    const float* p_att_w  = (const float*)d_in[10];
    const float* p_att_b  = (const float*)d_in[11];
    const float* p_le1_w  = (const float*)d_in[12];
    const float* p_le1_b  = (const float*)d_in[13];
    const float* p_le2_w  = (const float*)d_in[14];
    const float* p_le3_w  = (const float*)d_in[15];
    const float* p_le3_b  = (const float*)d_in[16];
    const float* lin1_w   = (const float*)d_in[17];
    const float* lin1_b   = (const float*)d_in[18];
    const float* lin2_w   = (const float*)d_in[19];
    const float* lin2_b   = (const float*)d_in[20];
    float* out = (float*)d_out;
    float* ws  = (float*)d_ws;

    const int E = in_sizes[1] / 2;   // 32768

    // workspace layout (floats)
    float* A1  = ws;                 // 16*128*128 = 262144
    float* hA  = A1  + 262144;       // 262144
    float* hB  = hA  + 262144;       // 262144
    float* A2w = hB  + 262144;       // 16*103*103 = 169744
    float* A3w = A2w + 169744;       // 16*83*83   = 110224
    float* xn  = A3w + 110224;       // 262144
    float* Tw  = xn  + 262144;       // 16*128*103 = 210944
    float* xsw = Tw  + 210944;       // 5*16*128   = 10240

    hipMemsetAsync(A1, 0, 262144 * sizeof(float), stream);
    kA_build<<<(E + 255) / 256, 256, 0, stream>>>(ei, A1, E);

    // conv0 (Cin=64) + gpool -> xs0
    k_conv<<<16, 512, 0, stream>>>(x, A1, c0_wrel, c0_brel, c0_wroot,
                                   hA, xsw + 0 * 2048, 128, 64, 128);
    // conv i=0 + gpool -> xs1
    k_conv<<<16, 512, 0, stream>>>(hA, A1, cw_rel, cb_rel, cw_root,
                                   hB, xsw + 1 * 2048, 128, 128, 128);
    // pool 1: n=128 -> k=103
    k_pool<<<16, 512, 0, stream>>>(hB, A1, hA, A2w, xn, Tw,
        p_lin_w, p_lin_b, p_att_w, p_att_b,
        p_le1_w, p_le1_b, p_le2_w, p_le3_w, p_le3_b, 128, 103);
    // conv i=1 + gpool -> xs2
    k_conv<<<16, 512, 0, stream>>>(hA, A2w, cw_rel + 16384, cb_rel + 128, cw_root + 16384,
                                   hB, xsw + 2 * 2048, 103, 128, 128);
    // conv i=2 + gpool -> xs3
    k_conv<<<16, 512, 0, stream>>>(hB, A2w, cw_rel + 2 * 16384, cb_rel + 2 * 128, cw_root + 2 * 16384,
                                   hA, xsw + 3 * 2048, 103, 128, 128);
    // pool 2: n=103 -> k=83
    k_pool<<<16, 512, 0, stream>>>(hA, A2w, hB, A3w, xn, Tw,
        p_lin_w + 16384, p_lin_b + 128, p_att_w + 256, p_att_b + 1,
        p_le1_w + 128, p_le1_b + 1, p_le2_w + 128, p_le3_w + 128, p_le3_b + 1, 103, 83);
    // conv i=3 + gpool -> xs4
    k_conv<<<16, 512, 0, stream>>>(hB, A3w, cw_rel + 3 * 16384, cb_rel + 3 * 128, cw_root + 3 * 16384,
                                   hA, xsw + 4 * 2048, 83, 128, 128);

    k_final<<<1, 256, 0, stream>>>(xsw, lin1_w, lin1_b, lin2_w, lin2_b, out);
}

// Round 2
// 1037.573 us; speedup vs baseline: 4.2272x; 4.2272x over previous
//
#include <hip/hip_runtime.h>

#define NEG_SLOPE 0.2f
typedef unsigned int u32;

// ------------------------------------------------------------ build bitmasks
__global__ __launch_bounds__(256) void k_build(const int* __restrict__ ei,
                                               u32* __restrict__ Mb,
                                               u32* __restrict__ Rb, int E)
{
    int e = blockIdx.x * 256 + threadIdx.x;
    if (e >= E) return;
    int s = ei[e], d = ei[E + e];
    int g = s >> 7, ls = s & 127, ld = d & 127;
    atomicOr(&Mb[(g * 128 + ld) * 4 + (ls >> 5)], 1u << (ls & 31));  // col mask (in-edges)
    atomicOr(&Rb[(g * 128 + ls) * 4 + (ld >> 5)], 1u << (ld & 31));  // row mask (out-edges)
}

// --------------------------------------------- agg = (A^T h)/deg, binary A
__global__ __launch_bounds__(512) void k_agg_mask(
    const float* __restrict__ h, const u32* __restrict__ Mb,
    float* __restrict__ agg, int n, int Cin)
{
    const int g = blockIdx.x;
    const int q4 = Cin >> 2;
    int idx = blockIdx.y * 512 + threadIdx.x;
    if (idx >= n * q4) return;
    int j = idx / q4, c4 = (idx - j * q4) << 2;
    const u32* m = Mb + (g * 128 + j) * 4;
    u32 m0 = m[0], m1 = m[1], m2 = m[2], m3 = m[3];
    float dv = fmaxf((float)(__popc(m0) + __popc(m1) + __popc(m2) + __popc(m3)), 1.0f);
    const float* hg = h + (size_t)g * n * Cin + c4;
    float sx = 0.f, sy = 0.f, sz = 0.f, sw = 0.f;
    u32 wds[4] = { m0, m1, m2, m3 };
    #pragma unroll
    for (int ww = 0; ww < 4; ++ww) {
        u32 u = wds[ww];
        while (u) {
            int i = (ww << 5) + __ffs(u) - 1; u &= u - 1u;
            float4 hv = *(const float4*)(hg + (size_t)i * Cin);
            sx += hv.x; sy += hv.y; sz += hv.z; sw += hv.w;
        }
    }
    float4 o; o.x = sx / dv; o.y = sy / dv; o.z = sz / dv; o.w = sw / dv;
    *(float4*)(agg + ((size_t)g * n + j) * Cin + c4) = o;
}

// --------------------------------------------- agg = (A^T h)/deg, dense A via A^T
__global__ __launch_bounds__(512) void k_agg_dense(
    const float* __restrict__ h, const float* __restrict__ AT,
    const u32* __restrict__ Mb, float* __restrict__ agg, int n)
{
    const int C = 128;
    const int g = blockIdx.x;
    int idx = blockIdx.y * 512 + threadIdx.x;
    if (idx >= n * 32) return;
    int j = idx >> 5, c4 = (idx & 31) << 2;
    const u32* m = Mb + (g * 128 + j) * 4;
    float dv = fmaxf((float)(__popc(m[0]) + __popc(m[1]) + __popc(m[2]) + __popc(m[3])), 1.0f);
    const float* Aj = AT + ((size_t)g * n + j) * n;     // AT[j][i] = A[i][j]
    const float* hg = h + (size_t)g * n * C + c4;
    float sx = 0.f, sy = 0.f, sz = 0.f, sw = 0.f;
    for (int i = 0; i < n; ++i) {
        float a = Aj[i];
        float4 hv = *(const float4*)(hg + (size_t)i * C);
        sx += a * hv.x; sy += a * hv.y; sz += a * hv.z; sw += a * hv.w;
    }
    float4 o; o.x = sx / dv; o.y = sy / dv; o.z = sz / dv; o.w = sw / dv;
    *(float4*)(agg + ((size_t)g * n + j) * C + c4) = o;
}

// ------- out = relu(agg@wrel^T + brel + h@wroot^T), fused gpool partial sums
// block 256 threads, tile 32 rows x 128 cols, 4x4 register tiles
__global__ __launch_bounds__(256) void k_out(
    const float* __restrict__ h, const float* __restrict__ agg,
    const float* __restrict__ wrel, const float* __restrict__ brel,
    const float* __restrict__ wroot,
    float* __restrict__ h_out, float* __restrict__ xs,
    int n, int Cin)
{
    const int g = blockIdx.x;
    const int jb = blockIdx.y * 32;
    const int tid = threadIdx.x;
    const int tx = tid & 31, ty = tid >> 5;            // ty 0..7
    __shared__ float Xs[32][34];
    __shared__ float Ws[128][34];
    float acc[4][4] = {};
    const int K = 2 * Cin;
    const float* hg = h + (size_t)g * n * Cin;
    const float* ag = agg + (size_t)g * n * Cin;

    for (int kk = 0; kk < K; kk += 32) {
        const float* Xsrc = (kk < Cin) ? (ag + kk) : (hg + kk - Cin);
        #pragma unroll
        for (int it = 0; it < 2; ++it) {
            int l = it * 256 + tid;
            int kp = l & 15, j = l >> 4;
            int jg = jb + j; if (jg > n - 1) jg = n - 1;
            float2 v = *(const float2*)(Xsrc + (size_t)jg * Cin + kp * 2);
            *(float2*)&Xs[j][kp * 2] = v;
        }
        const float* Wsrc = (kk < Cin) ? (wrel + kk) : (wroot + kk - Cin);
        #pragma unroll
        for (int it = 0; it < 8; ++it) {
            int l = it * 256 + tid;
            int kp = l & 15, c2 = l >> 4;
            float2 v = *(const float2*)(Wsrc + (size_t)c2 * Cin + kp * 2);
            *(float2*)&Ws[c2][kp * 2] = v;
        }
        __syncthreads();
        #pragma unroll
        for (int kp = 0; kp < 16; ++kp) {
            float2 xv[4], wv[4];
            #pragma unroll
            for (int r = 0; r < 4; ++r) xv[r] = *(const float2*)&Xs[ty * 4 + r][kp * 2];
            #pragma unroll
            for (int q = 0; q < 4; ++q) wv[q] = *(const float2*)&Ws[tx + 32 * q][kp * 2];
            #pragma unroll
            for (int r = 0; r < 4; ++r)
                #pragma unroll
                for (int q = 0; q < 4; ++q)
                    acc[r][q] += xv[r].x * wv[q].x + xv[r].y * wv[q].y;
        }
        __syncthreads();
    }

    float ps[4] = { 0.f, 0.f, 0.f, 0.f };
    #pragma unroll
    for (int q = 0; q < 4; ++q) {
        int c2 = tx + 32 * q;
        float b = brel[c2];
        #pragma unroll
        for (int r = 0; r < 4; ++r) {
            int jg = jb + ty * 4 + r;
            if (jg < n) {
                float v = fmaxf(acc[r][q] + b, 0.0f);
                h_out[((size_t)g * n + jg) * 128 + c2] = v;
                ps[q] += v;
            }
        }
    }
    // gpool partial: reduce over ty, one atomicAdd per column per block
    float* red = &Ws[0][0];
    #pragma unroll
    for (int q = 0; q < 4; ++q) red[ty * 128 + tx + 32 * q] = ps[q];
    __syncthreads();
    if (tid < 128) {
        float s = 0.f;
        #pragma unroll
        for (int t = 0; t < 8; ++t) s += red[t * 128 + tid];
        atomicAdd(&xs[g * 128 + tid], s / (float)n);
    }
}

// ------------------------------------------------------------- ASAP pooling
__global__ __launch_bounds__(512) void k_pool(
    const float* __restrict__ h_in,
    const u32* __restrict__ Mb_g, const u32* __restrict__ Rb_g,
    const float* __restrict__ A_in,               // null => binary A (use Rb)
    float* __restrict__ h_out,
    float* __restrict__ A_out, float* __restrict__ AT_out,
    u32* __restrict__ Mb_out, float* __restrict__ T_ws,
    const float* __restrict__ lin_w, const float* __restrict__ lin_b,
    const float* __restrict__ att_w, const float* __restrict__ att_bp,
    const float* __restrict__ le1_w, const float* __restrict__ le1_bp,
    const float* __restrict__ le2_w, const float* __restrict__ le3_w,
    const float* __restrict__ le3_bp,
    int n, int k)
{
    const int C = 128;
    const int g = blockIdx.x;
    const float* hg = h_in + (size_t)g * n * C;
    float* hog  = h_out  + (size_t)g * k * C;
    float* Aog  = A_out  + (size_t)g * k * k;
    float* ATog = AT_out + (size_t)g * k * k;
    float* Tg   = T_ws   + (size_t)g * n * k;

    __shared__ __align__(16) float h_s[128 * 128];   // h, later x_new
    __shared__ float S_s[128 * 129];
    __shared__ u32 Mb_s[128 * 4];
    __shared__ u32 Rb_s[128 * 4];
    __shared__ u32 Mb_t[128 * 4];
    __shared__ float v_s[128], qa_s[128], xa_s[128], deg_s[128], fit_s[128];
    __shared__ float a_s[128], b_s[128], c3_s[128];
    __shared__ int perm_s[128];
    __shared__ float c0_s;

    const int tid = threadIdx.x;
    const int lane = tid & 63, wid = tid >> 6;
    const int sst = (n & 1) ? n : (n + 1);
    const float att_b = att_bp[0];

    // ---- phase 0: loads + small precomputes
    for (int idx = tid; idx < n * 32; idx += 512)
        *(float4*)(h_s + idx * 4) = *(const float4*)(hg + idx * 4);
    Mb_t[tid & 511] = 0u;
    if (tid < 128) {
        float s = 0.f;
        for (int c2 = 0; c2 < C; ++c2) s += att_w[c2] * lin_w[c2 * C + tid];
        v_s[tid] = s;
    }
    if (wid == 0) {
        float s = att_w[lane] * lin_b[lane] + att_w[lane + 64] * lin_b[lane + 64];
        for (int off = 32; off; off >>= 1) s += __shfl_xor(s, off);
        if (lane == 0) c0_s = s;
    }
    for (int j = tid; j < n; j += 512) {
        u32 w0 = Mb_g[(g * 128 + j) * 4 + 0], w1 = Mb_g[(g * 128 + j) * 4 + 1];
        u32 w2 = Mb_g[(g * 128 + j) * 4 + 2], w3 = Mb_g[(g * 128 + j) * 4 + 3];
        int ww = j >> 5; u32 bit = 1u << (j & 31);     // diagonal
        if (ww == 0) w0 |= bit; else if (ww == 1) w1 |= bit;
        else if (ww == 2) w2 |= bit; else w3 |= bit;
        Mb_s[j * 4 + 0] = w0; Mb_s[j * 4 + 1] = w1;
        Mb_s[j * 4 + 2] = w2; Mb_s[j * 4 + 3] = w3;
        deg_s[j] = (float)(__popc(w0) + __popc(w1) + __popc(w2) + __popc(w3));
        if (A_in == nullptr) {
            u32 r0 = Rb_g[(g * 128 + j) * 4 + 0], r1 = Rb_g[(g * 128 + j) * 4 + 1];
            u32 r2 = Rb_g[(g * 128 + j) * 4 + 2], r3 = Rb_g[(g * 128 + j) * 4 + 3];
            if (ww == 0) r0 |= bit; else if (ww == 1) r1 |= bit;
            else if (ww == 2) r2 |= bit; else r3 |= bit;
            Rb_s[j * 4 + 0] = r0; Rb_s[j * 4 + 1] = r1;
            Rb_s[j * 4 + 2] = r2; Rb_s[j * 4 + 3] = r3;
        }
    }
    __syncthreads();

    // ---- phase 1: qa[j] = maskedColMax(h)·v + c0  (wave per column)
    for (int j = wid; j < n; j += 8) {
        const u32* mj = &Mb_s[j * 4];
        float acc = 0.f;
        #pragma unroll
        for (int half = 0; half < 2; ++half) {
            int c = lane + half * 64;
            float m = -1e30f;
            #pragma unroll
            for (int ww = 0; ww < 4; ++ww) {
                u32 u = mj[ww];
                while (u) {
                    int i = (ww << 5) + __ffs(u) - 1; u &= u - 1u;
                    m = fmaxf(m, h_s[i * C + c]);
                }
            }
            acc += m * v_s[c];
        }
        for (int off = 32; off; off >>= 1) acc += __shfl_xor(acc, off);
        if (lane == 0) qa_s[j] = acc + c0_s;
    }
    // xa[i] = h[i]·a_x  (wave per row)
    for (int i = wid; i < n; i += 8) {
        float s = h_s[i * C + lane] * att_w[C + lane]
                + h_s[i * C + 64 + lane] * att_w[C + 64 + lane];
        for (int off = 32; off; off >>= 1) s += __shfl_xor(s, off);
        if (lane == 0) xa_s[i] = s;
    }
    __syncthreads();

    // ---- phase 2: masked column softmax -> S_s (column-major)
    for (int j = wid; j < n; j += 8) {
        const float qaj = qa_s[j];
        const int i0 = lane, i1 = lane + 64;
        const bool b0 = (i0 < n) && ((Mb_s[j * 4 + (i0 >> 5)] >> (i0 & 31)) & 1u);
        const bool b1 = (i1 < n) && ((Mb_s[j * 4 + (i1 >> 5)] >> (i1 & 31)) & 1u);
        float l0 = -1e30f, l1 = -1e30f;
        if (b0) { float t = xa_s[i0] + qaj + att_b; l0 = (t >= 0.f) ? t : NEG_SLOPE * t; }
        if (b1) { float t = xa_s[i1] + qaj + att_b; l1 = (t >= 0.f) ? t : NEG_SLOPE * t; }
        float m = fmaxf(l0, l1);
        for (int off = 32; off; off >>= 1) m = fmaxf(m, __shfl_xor(m, off));
        float e0 = b0 ? expf(l0 - m) : 0.f;
        float e1 = b1 ? expf(l1 - m) : 0.f;
        float s = e0 + e1;
        for (int off = 32; off; off >>= 1) s += __shfl_xor(s, off);
        if (i0 < n) S_s[j * sst + i0] = e0 / s;
        if (i1 < n) S_s[j * sst + i1] = e1 / s;
    }
    __syncthreads();

    // ---- phase 3: x_new = S^T h into registers, then overwrite h_s
    float4 xr[8];
    #pragma unroll
    for (int it = 0; it < 8; ++it) {
        int idx = it * 512 + tid;
        if (idx < n * 32) {
            int j = idx >> 5, c4 = (idx & 31) << 2;
            const float* Sj = S_s + j * sst;
            float sx = 0.f, sy = 0.f, sz = 0.f, sw = 0.f;
            for (int i = 0; i < n; ++i) {
                float sv = Sj[i];
                float4 hv = *(const float4*)(h_s + i * C + c4);
                sx += sv * hv.x; sy += sv * hv.y; sz += sv * hv.z; sw += sv * hv.w;
            }
            xr[it] = make_float4(sx, sy, sz, sw);
        }
    }
    __syncthreads();
    #pragma unroll
    for (int it = 0; it < 8; ++it) {
        int idx = it * 512 + tid;
        if (idx < n * 32)
            *(float4*)(h_s + (idx >> 5) * C + ((idx & 31) << 2)) = xr[it];
    }
    __syncthreads();

    // ---- phase 4: a,b,c3 per row of x_new
    for (int j = wid; j < n; j += 8) {
        float x0 = h_s[j * C + lane], x1 = h_s[j * C + 64 + lane];
        float s1 = x0 * le1_w[lane] + x1 * le1_w[64 + lane];
        float s2 = x0 * le2_w[lane] + x1 * le2_w[64 + lane];
        float s3 = x0 * le3_w[lane] + x1 * le3_w[64 + lane];
        for (int off = 32; off; off >>= 1) {
            s1 += __shfl_xor(s1, off);
            s2 += __shfl_xor(s2, off);
            s3 += __shfl_xor(s3, off);
        }
        if (lane == 0) { a_s[j] = s1 + le1_bp[0]; b_s[j] = s2; c3_s[j] = s3; }
    }
    __syncthreads();

    // ---- phase 5: fitness
    for (int j = tid; j < n; j += 512) {
        const u32* mj = &Mb_s[j * 4];
        float s = 0.f;
        #pragma unroll
        for (int ww = 0; ww < 4; ++ww) {
            u32 u = mj[ww];
            while (u) { int i = (ww << 5) + __ffs(u) - 1; u &= u - 1u; s += a_s[i]; }
        }
        float f = s - deg_s[j] * b_s[j] + c3_s[j] + le3_bp[0];
        fit_s[j] = 1.0f / (1.0f + expf(-f));
    }
    __syncthreads();

    // ---- phase 6: top-k by rank (ties -> lower index, matches lax.top_k)
    for (int j = tid; j < n; j += 512) {
        float fj = fit_s[j];
        int r = 0;
        for (int j2 = 0; j2 < n; ++j2) {
            float f2 = fit_s[j2];
            if (f2 > fj || (f2 == fj && j2 < j)) ++r;
        }
        if (r < k) perm_s[r] = j;
    }
    __syncthreads();

    // ---- phase 7: h_out
    for (int idx = tid; idx < k * 32; idx += 512) {
        int r = idx >> 5, c4 = (idx & 31) << 2;
        int p = perm_s[r]; float f = fit_s[p];
        float4 v = *(const float4*)(h_s + p * C + c4);
        v.x *= f; v.y *= f; v.z *= f; v.w *= f;
        *(float4*)(hog + r * C + c4) = v;
    }

    // ---- phase 8: T = A_d @ S_sel
    if (A_in == nullptr) {
        for (int idx = tid; idx < n * k; idx += 512) {
            int i = idx / k, cc = idx - i * k;
            const float* Sp = S_s + perm_s[cc] * sst;
            const u32* ri = &Rb_s[i * 4];
            float s = 0.f;
            #pragma unroll
            for (int ww = 0; ww < 4; ++ww) {
                u32 u = ri[ww];
                while (u) { int j = (ww << 5) + __ffs(u) - 1; u &= u - 1u; s += Sp[j]; }
            }
            Tg[idx] = s;
        }
    } else {
        const float* Ag = A_in + (size_t)g * n * n;
        for (int idx = tid; idx < n * k; idx += 512) {
            int i = idx / k, cc = idx - i * k;
            const float* Sp = S_s + perm_s[cc] * sst;
            const float* Ai = Ag + (size_t)i * n;
            float s = 0.f;
            for (int j = 0; j < n; ++j) s += Ai[j] * Sp[j];
            Tg[idx] = s;
        }
    }
    __syncthreads();

    // ---- phase 9: A2 = S_sel^T @ T (unit diag) + transpose + nonzero bitmask
    for (int idx = tid; idx < k * k; idx += 512) {
        int r = idx / k, cc = idx - r * k;
        const float* Sr = S_s + perm_s[r] * sst;
        float s = 0.f;
        for (int i = 0; i < n; ++i) s += Sr[i] * Tg[i * k + cc];
        float val = (r == cc) ? 1.0f : s;
        Aog[idx] = val;
        ATog[(size_t)cc * k + r] = val;
        if (val != 0.0f) atomicOr(&Mb_t[cc * 4 + (r >> 5)], 1u << (r & 31));
    }
    __syncthreads();
    for (int t2 = tid; t2 < k * 4; t2 += 512)
        Mb_out[(g * 128 + (t2 >> 2)) * 4 + (t2 & 3)] = Mb_t[t2];
}

// ------------------------------------------------------------- classifier ---
__global__ __launch_bounds__(256) void k_final(
    const float* __restrict__ xs,     // [5][16][128] (already means)
    const float* __restrict__ w1, const float* __restrict__ b1,
    const float* __restrict__ w2, const float* __restrict__ b2,
    float* __restrict__ out)
{
    __shared__ float z1[16 * 128];
    const int tid = threadIdx.x;
    for (int idx = tid; idx < 2048; idx += blockDim.x) {
        int g = idx >> 7, c2 = idx & 127;
        const float* wrow = w1 + (size_t)c2 * 640;
        float s = b1[c2];
        for (int t = 0; t < 5; ++t) {
            const float4* xv = (const float4*)(xs + t * 2048 + g * 128);
            const float4* wv = (const float4*)(wrow + t * 128);
            #pragma unroll
            for (int c4 = 0; c4 < 32; ++c4) {
                float4 a = xv[c4], b = wv[c4];
                s += a.x * b.x + a.y * b.y + a.z * b.z + a.w * b.w;
            }
        }
        z1[idx] = fmaxf(s, 0.0f);
    }
    __syncthreads();
    if (tid < 16) {
        float za = b2[0], zb = b2[1];
        for (int c = 0; c < 128; ++c) {
            float zv = z1[tid * 128 + c];
            za += zv * w2[c];
            zb += zv * w2[128 + c];
        }
        float m = fmaxf(za, zb);
        float lse = m + logf(expf(za - m) + expf(zb - m));
        out[tid * 2 + 0] = za - lse;
        out[tid * 2 + 1] = zb - lse;
    }
}

// ---------------------------------------------------------------------------
extern "C" void kernel_launch(void* const* d_in, const int* in_sizes, int n_in,
                              void* d_out, int out_size, void* d_ws, size_t ws_size,
                              hipStream_t stream)
{
    (void)n_in; (void)out_size; (void)ws_size;
    const float* x        = (const float*)d_in[0];
    const int*   ei       = (const int*)  d_in[1];
    const float* c0_wrel  = (const float*)d_in[2];
    const float* c0_brel  = (const float*)d_in[3];
    const float* c0_wroot = (const float*)d_in[4];
    const float* cw_rel   = (const float*)d_in[5];
    const float* cb_rel   = (const float*)d_in[6];
    const float* cw_root  = (const float*)d_in[7];
    const float* p_lin_w  = (const float*)d_in[8];
    const float* p_lin_b  = (const float*)d_in[9];
    const float* p_att_w  = (const float*)d_in[10];
    const float* p_att_b  = (const float*)d_in[11];
    const float* p_le1_w  = (const float*)d_in[12];
    const float* p_le1_b  = (const float*)d_in[13];
    const float* p_le2_w  = (const float*)d_in[14];
    const float* p_le3_w  = (const float*)d_in[15];
    const float* p_le3_b  = (const float*)d_in[16];
    const float* lin1_w   = (const float*)d_in[17];
    const float* lin1_b   = (const float*)d_in[18];
    const float* lin2_w   = (const float*)d_in[19];
    const float* lin2_b   = (const float*)d_in[20];
    float* out = (float*)d_out;

    const int E = in_sizes[1] / 2;   // 32768

    // workspace layout
    u32*   Mb1 = (u32*)d_ws;                  //  8192 u32
    u32*   Rb1 = Mb1 + 8192;                  //  8192 u32
    float* xsf = (float*)(Rb1 + 8192);        // 10240 f32 (5 x 16 x 128)
    u32*   Mb2 = (u32*)(xsf + 10240);         //  8192 u32
    u32*   Mb3 = Mb2 + 8192;                  //  8192 u32
    float* agg = (float*)(Mb3 + 8192);        // 262144 f32 (also pool T scratch)
    float* hA  = agg + 262144;                // 262144
    float* hB  = hA  + 262144;                // 262144
    float* A2  = hB  + 262144;                // 169744
    float* A2T = A2  + 169744;                // 169744
    float* A3  = A2T + 169744;                // 110224
    float* A3T = A3  + 110224;                // 110224

    // zero: Mb1 | Rb1 | xs (contiguous)
    hipMemsetAsync(d_ws, 0, (8192 + 8192) * 4 + 10240 * 4, stream);
    k_build<<<(E + 255) / 256, 256, 0, stream>>>(ei, Mb1, Rb1, E);

    // conv0: Cin=64
    k_agg_mask<<<dim3(16, 4), 512, 0, stream>>>(x, Mb1, agg, 128, 64);
    k_out<<<dim3(16, 4), 256, 0, stream>>>(x, agg, c0_wrel, c0_brel, c0_wroot,
                                           hA, xsf + 0 * 2048, 128, 64);
    // conv1
    k_agg_mask<<<dim3(16, 8), 512, 0, stream>>>(hA, Mb1, agg, 128, 128);
    k_out<<<dim3(16, 4), 256, 0, stream>>>(hA, agg, cw_rel, cb_rel, cw_root,
                                           hB, xsf + 1 * 2048, 128, 128);
    // pool1: 128 -> 103
    k_pool<<<16, 512, 0, stream>>>(hB, Mb1, Rb1, nullptr, hA, A2, A2T, Mb2, agg,
        p_lin_w, p_lin_b, p_att_w, p_att_b,
        p_le1_w, p_le1_b, p_le2_w, p_le3_w, p_le3_b, 128, 103);
    // conv2
    k_agg_dense<<<dim3(16, 7), 512, 0, stream>>>(hA, A2T, Mb2, agg, 103);
    k_out<<<dim3(16, 4), 256, 0, stream>>>(hA, agg, cw_rel + 16384, cb_rel + 128,
                                           cw_root + 16384, hB, xsf + 2 * 2048, 103, 128);
    // conv3
    k_agg_dense<<<dim3(16, 7), 512, 0, stream>>>(hB, A2T, Mb2, agg, 103);
    k_out<<<dim3(16, 4), 256, 0, stream>>>(hB, agg, cw_rel + 2 * 16384, cb_rel + 2 * 128,
                                           cw_root + 2 * 16384, hA, xsf + 3 * 2048, 103, 128);
    // pool2: 103 -> 83
    k_pool<<<16, 512, 0, stream>>>(hA, Mb2, Rb1, A2, hB, A3, A3T, Mb3, agg,
        p_lin_w + 16384, p_lin_b + 128, p_att_w + 256, p_att_b + 1,
        p_le1_w + 128, p_le1_b + 1, p_le2_w + 128, p_le3_w + 128, p_le3_b + 1, 103, 83);
    // conv4
    k_agg_dense<<<dim3(16, 6), 512, 0, stream>>>(hB, A3T, Mb3, agg, 83);
    k_out<<<dim3(16, 3), 256, 0, stream>>>(hB, agg, cw_rel + 3 * 16384, cb_rel + 3 * 128,
                                           cw_root + 3 * 16384, hA, xsf + 4 * 2048, 83, 128);

    k_final<<<1, 256, 0, stream>>>(xsf, lin1_w, lin1_b, lin2_w, lin2_b, out);
}

// Round 3
// 946.372 us; speedup vs baseline: 4.6345x; 1.0964x over previous
//
#include <hip/hip_runtime.h>

#define NEG_SLOPE 0.2f
typedef unsigned int u32;

// ------------------------------------------------------------ build bitmasks
__global__ __launch_bounds__(256) void k_build(const int* __restrict__ ei,
                                               u32* __restrict__ Mb,
                                               u32* __restrict__ Rb, int E)
{
    int e = blockIdx.x * 256 + threadIdx.x;
    if (e >= E) return;
    int s = ei[e], d = ei[E + e];
    int g = s >> 7, ls = s & 127, ld = d & 127;
    atomicOr(&Mb[(g * 128 + ld) * 4 + (ls >> 5)], 1u << (ls & 31));  // col mask (in-edges)
    atomicOr(&Rb[(g * 128 + ls) * 4 + (ld >> 5)], 1u << (ld & 31));  // row mask (out-edges)
}

// --------------------------------------------- agg = (A^T h)/deg, binary A
__global__ __launch_bounds__(512) void k_agg_mask(
    const float* __restrict__ h, const u32* __restrict__ Mb,
    float* __restrict__ agg, int n, int Cin)
{
    const int g = blockIdx.x;
    const int q4 = Cin >> 2;
    int idx = blockIdx.y * 512 + threadIdx.x;
    if (idx >= n * q4) return;
    int j = idx / q4, c4 = (idx - j * q4) << 2;
    const u32* m = Mb + (g * 128 + j) * 4;
    u32 m0 = m[0], m1 = m[1], m2 = m[2], m3 = m[3];
    float dv = fmaxf((float)(__popc(m0) + __popc(m1) + __popc(m2) + __popc(m3)), 1.0f);
    const float* hg = h + (size_t)g * n * Cin + c4;
    float sx = 0.f, sy = 0.f, sz = 0.f, sw = 0.f;
    u32 wds[4] = { m0, m1, m2, m3 };
    #pragma unroll
    for (int ww = 0; ww < 4; ++ww) {
        u32 u = wds[ww];
        while (u) {
            int i = (ww << 5) + __ffs(u) - 1; u &= u - 1u;
            float4 hv = *(const float4*)(hg + (size_t)i * Cin);
            sx += hv.x; sy += hv.y; sz += hv.z; sw += hv.w;
        }
    }
    float4 o; o.x = sx / dv; o.y = sy / dv; o.z = sz / dv; o.w = sw / dv;
    *(float4*)(agg + ((size_t)g * n + j) * Cin + c4) = o;
}

// --------------------------------------------- agg = (A^T h)/deg, dense A via A^T
__global__ __launch_bounds__(512) void k_agg_dense(
    const float* __restrict__ h, const float* __restrict__ AT,
    const u32* __restrict__ Mb, float* __restrict__ agg, int n)
{
    const int C = 128;
    const int g = blockIdx.x;
    int idx = blockIdx.y * 512 + threadIdx.x;
    if (idx >= n * 32) return;
    int j = idx >> 5, c4 = (idx & 31) << 2;
    const u32* m = Mb + (g * 128 + j) * 4;
    float dv = fmaxf((float)(__popc(m[0]) + __popc(m[1]) + __popc(m[2]) + __popc(m[3])), 1.0f);
    const float* Aj = AT + ((size_t)g * n + j) * n;     // AT[j][i] = A[i][j]
    const float* hg = h + (size_t)g * n * C + c4;
    float sx = 0.f, sy = 0.f, sz = 0.f, sw = 0.f;
    for (int i = 0; i < n; ++i) {
        float a = Aj[i];
        float4 hv = *(const float4*)(hg + (size_t)i * C);
        sx += a * hv.x; sy += a * hv.y; sz += a * hv.z; sw += a * hv.w;
    }
    float4 o; o.x = sx / dv; o.y = sy / dv; o.z = sz / dv; o.w = sw / dv;
    *(float4*)(agg + ((size_t)g * n + j) * C + c4) = o;
}

// ------- out = relu(agg@wrel^T + brel + h@wroot^T), fused gpool partial sums
__global__ __launch_bounds__(256) void k_out(
    const float* __restrict__ h, const float* __restrict__ agg,
    const float* __restrict__ wrel, const float* __restrict__ brel,
    const float* __restrict__ wroot,
    float* __restrict__ h_out, float* __restrict__ xs,
    int n, int Cin)
{
    const int g = blockIdx.x;
    const int jb = blockIdx.y * 32;
    const int tid = threadIdx.x;
    const int tx = tid & 31, ty = tid >> 5;            // ty 0..7
    __shared__ float Xs[32][34];
    __shared__ float Ws[128][34];
    float acc[4][4] = {};
    const int K = 2 * Cin;
    const float* hg = h + (size_t)g * n * Cin;
    const float* ag = agg + (size_t)g * n * Cin;

    for (int kk = 0; kk < K; kk += 32) {
        const float* Xsrc = (kk < Cin) ? (ag + kk) : (hg + kk - Cin);
        #pragma unroll
        for (int it = 0; it < 2; ++it) {
            int l = it * 256 + tid;
            int kp = l & 15, j = l >> 4;
            int jg = jb + j; if (jg > n - 1) jg = n - 1;
            float2 v = *(const float2*)(Xsrc + (size_t)jg * Cin + kp * 2);
            *(float2*)&Xs[j][kp * 2] = v;
        }
        const float* Wsrc = (kk < Cin) ? (wrel + kk) : (wroot + kk - Cin);
        #pragma unroll
        for (int it = 0; it < 8; ++it) {
            int l = it * 256 + tid;
            int kp = l & 15, c2 = l >> 4;
            float2 v = *(const float2*)(Wsrc + (size_t)c2 * Cin + kp * 2);
            *(float2*)&Ws[c2][kp * 2] = v;
        }
        __syncthreads();
        #pragma unroll
        for (int kp = 0; kp < 16; ++kp) {
            float2 xv[4], wv[4];
            #pragma unroll
            for (int r = 0; r < 4; ++r) xv[r] = *(const float2*)&Xs[ty * 4 + r][kp * 2];
            #pragma unroll
            for (int q = 0; q < 4; ++q) wv[q] = *(const float2*)&Ws[tx + 32 * q][kp * 2];
            #pragma unroll
            for (int r = 0; r < 4; ++r)
                #pragma unroll
                for (int q = 0; q < 4; ++q)
                    acc[r][q] += xv[r].x * wv[q].x + xv[r].y * wv[q].y;
        }
        __syncthreads();
    }

    float ps[4] = { 0.f, 0.f, 0.f, 0.f };
    #pragma unroll
    for (int q = 0; q < 4; ++q) {
        int c2 = tx + 32 * q;
        float b = brel[c2];
        #pragma unroll
        for (int r = 0; r < 4; ++r) {
            int jg = jb + ty * 4 + r;
            if (jg < n) {
                float v = fmaxf(acc[r][q] + b, 0.0f);
                h_out[((size_t)g * n + jg) * 128 + c2] = v;
                ps[q] += v;
            }
        }
    }
    float* red = &Ws[0][0];
    #pragma unroll
    for (int q = 0; q < 4; ++q) red[ty * 128 + tx + 32 * q] = ps[q];
    __syncthreads();
    if (tid < 128) {
        float s = 0.f;
        #pragma unroll
        for (int t = 0; t < 8; ++t) s += red[t * 128 + tid];
        atomicAdd(&xs[g * 128 + tid], s / (float)n);
    }
}

// ---------------------------------------- pool stage 1: S, masks, deg
__global__ __launch_bounds__(512) void k_pool_S(
    const float* __restrict__ h_in, const u32* __restrict__ Mb_g,
    float* __restrict__ S_cm, u32* __restrict__ Mbd, float* __restrict__ deg_g,
    const float* __restrict__ lin_w, const float* __restrict__ lin_b,
    const float* __restrict__ att_w, const float* __restrict__ att_bp,
    int n)
{
    const int C = 128;
    const int g = blockIdx.x;
    const float* hg = h_in + (size_t)g * n * C;
    __shared__ __align__(16) float h_s[128 * 128];
    __shared__ u32 Mb_s[128 * 4];
    __shared__ float v_s[128], qa_s[128], xa_s[128];
    __shared__ float c0_s;
    const int tid = threadIdx.x, lane = tid & 63, wid = tid >> 6;
    const float att_b = att_bp[0];

    for (int idx = tid; idx < n * 32; idx += 512)
        *(float4*)(h_s + idx * 4) = *(const float4*)(hg + idx * 4);
    if (tid < 128) {
        float s = 0.f;
        for (int c2 = 0; c2 < C; ++c2) s += att_w[c2] * lin_w[c2 * C + tid];
        v_s[tid] = s;
    }
    if (wid == 0) {
        float s = att_w[lane] * lin_b[lane] + att_w[lane + 64] * lin_b[lane + 64];
        for (int off = 32; off; off >>= 1) s += __shfl_xor(s, off);
        if (lane == 0) c0_s = s;
    }
    for (int j = tid; j < n; j += 512) {
        u32 w0 = Mb_g[(g * 128 + j) * 4 + 0], w1 = Mb_g[(g * 128 + j) * 4 + 1];
        u32 w2 = Mb_g[(g * 128 + j) * 4 + 2], w3 = Mb_g[(g * 128 + j) * 4 + 3];
        int ww = j >> 5; u32 bit = 1u << (j & 31);     // diagonal
        if (ww == 0) w0 |= bit; else if (ww == 1) w1 |= bit;
        else if (ww == 2) w2 |= bit; else w3 |= bit;
        Mb_s[j * 4 + 0] = w0; Mb_s[j * 4 + 1] = w1;
        Mb_s[j * 4 + 2] = w2; Mb_s[j * 4 + 3] = w3;
        Mbd[(g * 128 + j) * 4 + 0] = w0; Mbd[(g * 128 + j) * 4 + 1] = w1;
        Mbd[(g * 128 + j) * 4 + 2] = w2; Mbd[(g * 128 + j) * 4 + 3] = w3;
        deg_g[g * 128 + j] = (float)(__popc(w0) + __popc(w1) + __popc(w2) + __popc(w3));
    }
    __syncthreads();

    // qa[j] = maskedColMax(h)·v + c0  (wave per column)
    for (int j = wid; j < n; j += 8) {
        const u32* mj = &Mb_s[j * 4];
        float acc = 0.f;
        #pragma unroll
        for (int half = 0; half < 2; ++half) {
            int c = lane + half * 64;
            float m = -1e30f;
            #pragma unroll
            for (int ww = 0; ww < 4; ++ww) {
                u32 u = mj[ww];
                while (u) {
                    int i = (ww << 5) + __ffs(u) - 1; u &= u - 1u;
                    m = fmaxf(m, h_s[i * C + c]);
                }
            }
            acc += m * v_s[c];
        }
        for (int off = 32; off; off >>= 1) acc += __shfl_xor(acc, off);
        if (lane == 0) qa_s[j] = acc + c0_s;
    }
    // xa[i] = h[i]·a_x  (wave per row)
    for (int i = wid; i < n; i += 8) {
        float s = h_s[i * C + lane] * att_w[C + lane]
                + h_s[i * C + 64 + lane] * att_w[C + 64 + lane];
        for (int off = 32; off; off >>= 1) s += __shfl_xor(s, off);
        if (lane == 0) xa_s[i] = s;
    }
    __syncthreads();

    // masked column softmax -> S_cm[g][j][i] (row j = column j of S)
    for (int j = wid; j < n; j += 8) {
        const float qaj = qa_s[j];
        const int i0 = lane, i1 = lane + 64;
        const bool b0 = (i0 < n) && ((Mb_s[j * 4 + (i0 >> 5)] >> (i0 & 31)) & 1u);
        const bool b1 = (i1 < n) && ((Mb_s[j * 4 + (i1 >> 5)] >> (i1 & 31)) & 1u);
        float l0 = -1e30f, l1 = -1e30f;
        if (b0) { float t = xa_s[i0] + qaj + att_b; l0 = (t >= 0.f) ? t : NEG_SLOPE * t; }
        if (b1) { float t = xa_s[i1] + qaj + att_b; l1 = (t >= 0.f) ? t : NEG_SLOPE * t; }
        float m = fmaxf(l0, l1);
        for (int off = 32; off; off >>= 1) m = fmaxf(m, __shfl_xor(m, off));
        float e0 = b0 ? expf(l0 - m) : 0.f;
        float e1 = b1 ? expf(l1 - m) : 0.f;
        float s = e0 + e1;
        for (int off = 32; off; off >>= 1) s += __shfl_xor(s, off);
        float* Sj = S_cm + ((size_t)g * 128 + j) * 128;
        if (i0 < n) Sj[i0] = e0 / s;
        if (i1 < n) Sj[i1] = e1 / s;
    }
}

// ---------------------------------------- pool stage 2: x_new = S_cm @ h
__global__ __launch_bounds__(512) void k_xnew(
    const float* __restrict__ S_cm, const float* __restrict__ h,
    float* __restrict__ xn, int n)
{
    const int g = blockIdx.x;
    int idx = blockIdx.y * 512 + threadIdx.x;
    if (idx >= n * 32) return;
    int j = idx >> 5, c4 = (idx & 31) << 2;
    const float* Sj = S_cm + ((size_t)g * 128 + j) * 128;
    const float* hg = h + (size_t)g * n * 128 + c4;
    float sx = 0.f, sy = 0.f, sz = 0.f, sw = 0.f;
    for (int i = 0; i < n; ++i) {
        float sv = Sj[i];
        float4 hv = *(const float4*)(hg + (size_t)i * 128);
        sx += sv * hv.x; sy += sv * hv.y; sz += sv * hv.z; sw += sv * hv.w;
    }
    float4 o; o.x = sx; o.y = sy; o.z = sz; o.w = sw;
    *(float4*)(xn + ((size_t)g * 128 + j) * 128 + c4) = o;
}

// ------------- pool stage 3: fitness, top-k, h_out, Sselr gathers
__global__ __launch_bounds__(512) void k_fit(
    const float* __restrict__ xn, const u32* __restrict__ Mbd,
    const float* __restrict__ deg_g, const float* __restrict__ S_cm,
    const float* __restrict__ le1_w, const float* __restrict__ le1_bp,
    const float* __restrict__ le2_w, const float* __restrict__ le3_w,
    const float* __restrict__ le3_bp,
    float* __restrict__ h_out, float* __restrict__ Sselr, float* __restrict__ SselrT,
    int n, int k, int kpad)
{
    const int g = blockIdx.x;
    const float* xg = xn + (size_t)g * 128 * 128;
    __shared__ float a_s[128], b_s[128], c3_s[128], fit_s[128];
    __shared__ int perm_s[128];
    const int tid = threadIdx.x, lane = tid & 63, wid = tid >> 6;

    for (int j = wid; j < n; j += 8) {
        float x0 = xg[j * 128 + lane], x1 = xg[j * 128 + 64 + lane];
        float s1 = x0 * le1_w[lane] + x1 * le1_w[64 + lane];
        float s2 = x0 * le2_w[lane] + x1 * le2_w[64 + lane];
        float s3 = x0 * le3_w[lane] + x1 * le3_w[64 + lane];
        for (int off = 32; off; off >>= 1) {
            s1 += __shfl_xor(s1, off);
            s2 += __shfl_xor(s2, off);
            s3 += __shfl_xor(s3, off);
        }
        if (lane == 0) { a_s[j] = s1 + le1_bp[0]; b_s[j] = s2; c3_s[j] = s3; }
    }
    __syncthreads();
    for (int j = tid; j < n; j += 512) {
        const u32* mj = Mbd + (g * 128 + j) * 4;
        float s = 0.f;
        #pragma unroll
        for (int ww = 0; ww < 4; ++ww) {
            u32 u = mj[ww];
            while (u) { int i = (ww << 5) + __ffs(u) - 1; u &= u - 1u; s += a_s[i]; }
        }
        float f = s - deg_g[g * 128 + j] * b_s[j] + c3_s[j] + le3_bp[0];
        fit_s[j] = 1.0f / (1.0f + expf(-f));
    }
    __syncthreads();
    // top-k by rank (ties -> lower index, matches lax.top_k)
    for (int j = tid; j < n; j += 512) {
        float fj = fit_s[j];
        int r = 0;
        for (int j2 = 0; j2 < n; ++j2) {
            float f2 = fit_s[j2];
            if (f2 > fj || (f2 == fj && j2 < j)) ++r;
        }
        if (r < k) perm_s[r] = j;
    }
    __syncthreads();
    // h_out[r] = x_new[perm[r]] * fit[perm[r]]
    for (int idx = tid; idx < k * 32; idx += 512) {
        int r = idx >> 5, c4 = (idx & 31) << 2;
        int p = perm_s[r]; float f = fit_s[p];
        float4 v = *(const float4*)(xg + p * 128 + c4);
        v.x *= f; v.y *= f; v.z *= f; v.w *= f;
        *(float4*)(h_out + ((size_t)g * k + r) * 128 + c4) = v;
    }
    // SselrT[r][i] = S_cm[perm[r]][i]   (row gather, coalesced)
    for (int idx = tid; idx < k * 32; idx += 512) {
        int r = idx >> 5, c4 = (idx & 31) << 2;
        float4 v = *(const float4*)(S_cm + ((size_t)g * 128 + perm_s[r]) * 128 + c4);
        *(float4*)(SselrT + ((size_t)g * 128 + r) * 128 + c4) = v;
    }
    // Sselr[i][cc] = S_cm[perm[cc]][i]  (coalesced reads, scattered 4B writes)
    for (int idx = tid; idx < k * n; idx += 512) {
        int cc = idx / n, i = idx - cc * n;
        Sselr[((size_t)g * 128 + i) * kpad + cc] =
            S_cm[((size_t)g * 128 + perm_s[cc]) * 128 + i];
    }
}

// ---------------------------------------- pool stage 4: T = A_d @ S_sel
__global__ __launch_bounds__(512) void k_T_mask(
    const u32* __restrict__ Rb, const float* __restrict__ Sselr,
    float* __restrict__ T, int n, int k, int kpad)
{
    const int g = blockIdx.x;
    const int ccq = (k + 3) >> 2;
    int idx = blockIdx.y * 512 + threadIdx.x;
    if (idx >= n * ccq) return;
    int i = idx / ccq, c4 = (idx - i * ccq) << 2;
    u32 m[4];
    m[0] = Rb[(g * 128 + i) * 4 + 0]; m[1] = Rb[(g * 128 + i) * 4 + 1];
    m[2] = Rb[(g * 128 + i) * 4 + 2]; m[3] = Rb[(g * 128 + i) * 4 + 3];
    m[i >> 5] |= 1u << (i & 31);                      // diagonal
    float sx = 0.f, sy = 0.f, sz = 0.f, sw = 0.f;
    #pragma unroll
    for (int ww = 0; ww < 4; ++ww) {
        u32 u = m[ww];
        while (u) {
            int j = (ww << 5) + __ffs(u) - 1; u &= u - 1u;
            float4 v = *(const float4*)(Sselr + ((size_t)g * 128 + j) * kpad + c4);
            sx += v.x; sy += v.y; sz += v.z; sw += v.w;
        }
    }
    float4 o; o.x = sx; o.y = sy; o.z = sz; o.w = sw;
    *(float4*)(T + ((size_t)g * 128 + i) * kpad + c4) = o;
}

__global__ __launch_bounds__(512) void k_T_dense(
    const float* __restrict__ A, const float* __restrict__ Sselr,
    float* __restrict__ T, int n, int k, int kpad)
{
    const int g = blockIdx.x;
    const int ccq = (k + 3) >> 2;
    int idx = blockIdx.y * 512 + threadIdx.x;
    if (idx >= n * ccq) return;
    int i = idx / ccq, c4 = (idx - i * ccq) << 2;
    const float* Ai = A + ((size_t)g * n + i) * n;    // unit diag already present
    float sx = 0.f, sy = 0.f, sz = 0.f, sw = 0.f;
    for (int j = 0; j < n; ++j) {
        float a = Ai[j];
        float4 v = *(const float4*)(Sselr + ((size_t)g * 128 + j) * kpad + c4);
        sx += a * v.x; sy += a * v.y; sz += a * v.z; sw += a * v.w;
    }
    float4 o; o.x = sx; o.y = sy; o.z = sz; o.w = sw;
    *(float4*)(T + ((size_t)g * 128 + i) * kpad + c4) = o;
}

// ------------- pool stage 5: A2 = S_sel^T @ T (+diag, +transpose, +mask)
__global__ __launch_bounds__(512) void k_A2(
    const float* __restrict__ SselrT, const float* __restrict__ T,
    float* __restrict__ A_out, float* __restrict__ AT_out,
    u32* __restrict__ Mb_out, int n, int k, int kpad)
{
    const int g = blockIdx.x;
    int idx = blockIdx.y * 512 + threadIdx.x;
    if (idx >= k * k) return;
    int r = idx / k, cc = idx - r * k;
    const float* Sr = SselrT + ((size_t)g * 128 + r) * 128;
    const float* Tg = T + (size_t)g * 128 * kpad;
    float s = 0.f;
    for (int i = 0; i < n; ++i) s += Sr[i] * Tg[i * kpad + cc];
    float val = (r == cc) ? 1.0f : s;
    A_out[((size_t)g * k + r) * k + cc] = val;
    AT_out[((size_t)g * k + cc) * k + r] = val;
    if (val != 0.0f)
        atomicOr(&Mb_out[((size_t)g * 128 + cc) * 4 + (r >> 5)], 1u << (r & 31));
}

// ------------------------------------------------------------- classifier ---
__global__ __launch_bounds__(256) void k_final(
    const float* __restrict__ xs,     // [5][16][128]
    const float* __restrict__ w1, const float* __restrict__ b1,
    const float* __restrict__ w2, const float* __restrict__ b2,
    float* __restrict__ out)
{
    __shared__ float z1[16 * 128];
    const int tid = threadIdx.x;
    for (int idx = tid; idx < 2048; idx += blockDim.x) {
        int g = idx >> 7, c2 = idx & 127;
        const float* wrow = w1 + (size_t)c2 * 640;
        float s = b1[c2];
        for (int t = 0; t < 5; ++t) {
            const float4* xv = (const float4*)(xs + t * 2048 + g * 128);
            const float4* wv = (const float4*)(wrow + t * 128);
            #pragma unroll
            for (int c4 = 0; c4 < 32; ++c4) {
                float4 a = xv[c4], b = wv[c4];
                s += a.x * b.x + a.y * b.y + a.z * b.z + a.w * b.w;
            }
        }
        z1[idx] = fmaxf(s, 0.0f);
    }
    __syncthreads();
    if (tid < 16) {
        float za = b2[0], zb = b2[1];
        for (int c = 0; c < 128; ++c) {
            float zv = z1[tid * 128 + c];
            za += zv * w2[c];
            zb += zv * w2[128 + c];
        }
        float m = fmaxf(za, zb);
        float lse = m + logf(expf(za - m) + expf(zb - m));
        out[tid * 2 + 0] = za - lse;
        out[tid * 2 + 1] = zb - lse;
    }
}

// ---------------------------------------------------------------------------
extern "C" void kernel_launch(void* const* d_in, const int* in_sizes, int n_in,
                              void* d_out, int out_size, void* d_ws, size_t ws_size,
                              hipStream_t stream)
{
    (void)n_in; (void)out_size; (void)ws_size;
    const float* x        = (const float*)d_in[0];
    const int*   ei       = (const int*)  d_in[1];
    const float* c0_wrel  = (const float*)d_in[2];
    const float* c0_brel  = (const float*)d_in[3];
    const float* c0_wroot = (const float*)d_in[4];
    const float* cw_rel   = (const float*)d_in[5];
    const float* cb_rel   = (const float*)d_in[6];
    const float* cw_root  = (const float*)d_in[7];
    const float* p_lin_w  = (const float*)d_in[8];
    const float* p_lin_b  = (const float*)d_in[9];
    const float* p_att_w  = (const float*)d_in[10];
    const float* p_att_b  = (const float*)d_in[11];
    const float* p_le1_w  = (const float*)d_in[12];
    const float* p_le1_b  = (const float*)d_in[13];
    const float* p_le2_w  = (const float*)d_in[14];
    const float* p_le3_w  = (const float*)d_in[15];
    const float* p_le3_b  = (const float*)d_in[16];
    const float* lin1_w   = (const float*)d_in[17];
    const float* lin1_b   = (const float*)d_in[18];
    const float* lin2_w   = (const float*)d_in[19];
    const float* lin2_b   = (const float*)d_in[20];
    float* out = (float*)d_out;

    const int E = in_sizes[1] / 2;   // 32768

    // workspace layout (memset region first: Mb1|Rb1|xsf|Mb2|Mb3)
    u32*   Mb1 = (u32*)d_ws;                  //  8192
    u32*   Rb1 = Mb1 + 8192;                  //  8192
    float* xsf = (float*)(Rb1 + 8192);        // 10240
    u32*   Mb2 = (u32*)(xsf + 10240);         //  8192
    u32*   Mb3 = Mb2 + 8192;                  //  8192
    u32*   Mbd = Mb3 + 8192;                  //  8192
    float* degw = (float*)(Mbd + 8192);       //  2048
    float* agg = degw + 2048;                 // 262144 (aliased as T_ws in pools)
    float* hA  = agg + 262144;                // 262144
    float* hB  = hA  + 262144;                // 262144
    float* Scm = hB  + 262144;                // 262144
    float* xnw = Scm + 262144;                // 262144
    float* Ssr = xnw + 262144;                // 16*128*112 = 229376
    float* SsT = Ssr + 229376;                // 262144
    float* A2  = SsT + 262144;                // 169744
    float* A2T = A2  + 169744;                // 169744
    float* A3  = A2T + 169744;                // 110224
    float* A3T = A3  + 110224;                // 110224
    float* Tw  = agg;                         // alias: disjoint lifetime vs conv agg

    hipMemsetAsync(d_ws, 0, (8192 + 8192 + 10240 + 8192 + 8192) * 4, stream);
    k_build<<<(E + 255) / 256, 256, 0, stream>>>(ei, Mb1, Rb1, E);

    // conv0: Cin=64
    k_agg_mask<<<dim3(16, 4), 512, 0, stream>>>(x, Mb1, agg, 128, 64);
    k_out<<<dim3(16, 4), 256, 0, stream>>>(x, agg, c0_wrel, c0_brel, c0_wroot,
                                           hA, xsf + 0 * 2048, 128, 64);
    // conv1
    k_agg_mask<<<dim3(16, 8), 512, 0, stream>>>(hA, Mb1, agg, 128, 128);
    k_out<<<dim3(16, 4), 256, 0, stream>>>(hA, agg, cw_rel, cb_rel, cw_root,
                                           hB, xsf + 1 * 2048, 128, 128);
    // pool1: n=128 -> k=103 (kpad=112)
    k_pool_S<<<16, 512, 0, stream>>>(hB, Mb1, Scm, Mbd, degw,
                                     p_lin_w, p_lin_b, p_att_w, p_att_b, 128);
    k_xnew<<<dim3(16, 8), 512, 0, stream>>>(Scm, hB, xnw, 128);
    k_fit<<<16, 512, 0, stream>>>(xnw, Mbd, degw, Scm,
                                  p_le1_w, p_le1_b, p_le2_w, p_le3_w, p_le3_b,
                                  hA, Ssr, SsT, 128, 103, 112);
    k_T_mask<<<dim3(16, 7), 512, 0, stream>>>(Rb1, Ssr, Tw, 128, 103, 112);
    k_A2<<<dim3(16, 21), 512, 0, stream>>>(SsT, Tw, A2, A2T, Mb2, 128, 103, 112);
    // conv2
    k_agg_dense<<<dim3(16, 7), 512, 0, stream>>>(hA, A2T, Mb2, agg, 103);
    k_out<<<dim3(16, 4), 256, 0, stream>>>(hA, agg, cw_rel + 16384, cb_rel + 128,
                                           cw_root + 16384, hB, xsf + 2 * 2048, 103, 128);
    // conv3
    k_agg_dense<<<dim3(16, 7), 512, 0, stream>>>(hB, A2T, Mb2, agg, 103);
    k_out<<<dim3(16, 4), 256, 0, stream>>>(hB, agg, cw_rel + 2 * 16384, cb_rel + 2 * 128,
                                           cw_root + 2 * 16384, hA, xsf + 3 * 2048, 103, 128);
    // pool2: n=103 -> k=83 (kpad=96)
    k_pool_S<<<16, 512, 0, stream>>>(hA, Mb2, Scm, Mbd, degw,
                                     p_lin_w + 16384, p_lin_b + 128,
                                     p_att_w + 256, p_att_b + 1, 103);
    k_xnew<<<dim3(16, 7), 512, 0, stream>>>(Scm, hA, xnw, 103);
    k_fit<<<16, 512, 0, stream>>>(xnw, Mbd, degw, Scm,
                                  p_le1_w + 128, p_le1_b + 1, p_le2_w + 128,
                                  p_le3_w + 128, p_le3_b + 1,
                                  hB, Ssr, SsT, 103, 83, 96);
    k_T_dense<<<dim3(16, 5), 512, 0, stream>>>(A2, Ssr, Tw, 103, 83, 96);
    k_A2<<<dim3(16, 14), 512, 0, stream>>>(SsT, Tw, A3, A3T, Mb3, 103, 83, 96);
    // conv4
    k_agg_dense<<<dim3(16, 6), 512, 0, stream>>>(hB, A3T, Mb3, agg, 83);
    k_out<<<dim3(16, 3), 256, 0, stream>>>(hB, agg, cw_rel + 3 * 16384, cb_rel + 3 * 128,
                                           cw_root + 3 * 16384, hA, xsf + 4 * 2048, 83, 128);

    k_final<<<1, 256, 0, stream>>>(xsf, lin1_w, lin1_b, lin2_w, lin2_b, out);
}

// Round 4
// 769.728 us; speedup vs baseline: 5.6981x; 1.2295x over previous
//
#include <hip/hip_runtime.h>

#define NEG_SLOPE 0.2f
typedef unsigned int u32;

// ------------------------------------------------------------ build bitmasks
__global__ __launch_bounds__(256) void k_build(const int* __restrict__ ei,
                                               u32* __restrict__ Mb,
                                               u32* __restrict__ Rb, int E)
{
    int e = blockIdx.x * 256 + threadIdx.x;
    if (e >= E) return;
    int s = ei[e], d = ei[E + e];
    int g = s >> 7, ls = s & 127, ld = d & 127;
    atomicOr(&Mb[(g * 128 + ld) * 4 + (ls >> 5)], 1u << (ls & 31));  // col mask (in-edges)
    atomicOr(&Rb[(g * 128 + ls) * 4 + (ld >> 5)], 1u << (ld & 31));  // row mask (out-edges)
}

// ------------------------------------- precompute v = lin_w^T a_q, c0 = lin_b·a_q
__global__ __launch_bounds__(128) void k_prep(
    const float* __restrict__ lin_w, const float* __restrict__ lin_b,
    const float* __restrict__ att_w,
    float* __restrict__ v_out, float* __restrict__ c0_out)
{
    const int p = blockIdx.x;
    const float* lw = lin_w + p * 16384;
    const float* lb = lin_b + p * 128;
    const float* aw = att_w + p * 256;
    const int c = threadIdx.x;
    float s = 0.f;
    for (int c2 = 0; c2 < 128; ++c2) s += aw[c2] * lw[c2 * 128 + c];
    v_out[p * 128 + c] = s;
    if (c < 64) {
        float s0 = aw[c] * lb[c] + aw[c + 64] * lb[c + 64];
        for (int off = 32; off; off >>= 1) s0 += __shfl_xor(s0, off);
        if (c == 0) c0_out[p] = s0;
    }
}

// --------------------------------------------- agg = (A^T h)/deg, binary A
__global__ __launch_bounds__(512) void k_agg_mask(
    const float* __restrict__ h, const u32* __restrict__ Mb,
    float* __restrict__ agg, int n, int Cin)
{
    const int g = blockIdx.x;
    const int q4 = Cin >> 2;
    int idx = blockIdx.y * 512 + threadIdx.x;
    if (idx >= n * q4) return;
    int j = idx / q4, c4 = (idx - j * q4) << 2;
    const u32* m = Mb + (g * 128 + j) * 4;
    u32 m0 = m[0], m1 = m[1], m2 = m[2], m3 = m[3];
    float dv = fmaxf((float)(__popc(m0) + __popc(m1) + __popc(m2) + __popc(m3)), 1.0f);
    const float* hg = h + (size_t)g * n * Cin + c4;
    float sx = 0.f, sy = 0.f, sz = 0.f, sw = 0.f;
    u32 wds[4] = { m0, m1, m2, m3 };
    #pragma unroll
    for (int ww = 0; ww < 4; ++ww) {
        u32 u = wds[ww];
        while (u) {
            int i = (ww << 5) + __ffs(u) - 1; u &= u - 1u;
            float4 hv = *(const float4*)(hg + (size_t)i * Cin);
            sx += hv.x; sy += hv.y; sz += hv.z; sw += hv.w;
        }
    }
    float4 o; o.x = sx / dv; o.y = sy / dv; o.z = sz / dv; o.w = sw / dv;
    *(float4*)(agg + ((size_t)g * n + j) * Cin + c4) = o;
}

// --------------------------------------------- agg = (A^T h)/deg, dense A via A^T
__global__ __launch_bounds__(512) void k_agg_dense(
    const float* __restrict__ h, const float* __restrict__ AT,
    const u32* __restrict__ Mb, float* __restrict__ agg, int n)
{
    const int C = 128;
    const int g = blockIdx.x;
    int idx = blockIdx.y * 512 + threadIdx.x;
    if (idx >= n * 32) return;
    int j = idx >> 5, c4 = (idx & 31) << 2;
    const u32* m = Mb + (g * 128 + j) * 4;
    float dv = fmaxf((float)(__popc(m[0]) + __popc(m[1]) + __popc(m[2]) + __popc(m[3])), 1.0f);
    const float* Aj = AT + ((size_t)g * n + j) * n;     // AT[j][i] = A[i][j]
    const float* hg = h + (size_t)g * n * C + c4;
    float sx = 0.f, sy = 0.f, sz = 0.f, sw = 0.f;
    for (int i = 0; i < n; ++i) {
        float a = Aj[i];
        float4 hv = *(const float4*)(hg + (size_t)i * C);
        sx += a * hv.x; sy += a * hv.y; sz += a * hv.z; sw += a * hv.w;
    }
    float4 o; o.x = sx / dv; o.y = sy / dv; o.z = sz / dv; o.w = sw / dv;
    *(float4*)(agg + ((size_t)g * n + j) * C + c4) = o;
}

// ------- out = relu(agg@wrel^T + brel + h@wroot^T), fused gpool partial sums
__global__ __launch_bounds__(256) void k_out(
    const float* __restrict__ h, const float* __restrict__ agg,
    const float* __restrict__ wrel, const float* __restrict__ brel,
    const float* __restrict__ wroot,
    float* __restrict__ h_out, float* __restrict__ xs,
    int n, int Cin)
{
    const int g = blockIdx.x;
    const int jb = blockIdx.y * 32;
    const int tid = threadIdx.x;
    const int tx = tid & 31, ty = tid >> 5;            // ty 0..7
    __shared__ float Xs[32][34];
    __shared__ float Ws[128][34];
    float acc[4][4] = {};
    const int K = 2 * Cin;
    const float* hg = h + (size_t)g * n * Cin;
    const float* ag = agg + (size_t)g * n * Cin;

    for (int kk = 0; kk < K; kk += 32) {
        const float* Xsrc = (kk < Cin) ? (ag + kk) : (hg + kk - Cin);
        #pragma unroll
        for (int it = 0; it < 2; ++it) {
            int l = it * 256 + tid;
            int kp = l & 15, j = l >> 4;
            int jg = jb + j; if (jg > n - 1) jg = n - 1;
            float2 v = *(const float2*)(Xsrc + (size_t)jg * Cin + kp * 2);
            *(float2*)&Xs[j][kp * 2] = v;
        }
        const float* Wsrc = (kk < Cin) ? (wrel + kk) : (wroot + kk - Cin);
        #pragma unroll
        for (int it = 0; it < 8; ++it) {
            int l = it * 256 + tid;
            int kp = l & 15, c2 = l >> 4;
            float2 v = *(const float2*)(Wsrc + (size_t)c2 * Cin + kp * 2);
            *(float2*)&Ws[c2][kp * 2] = v;
        }
        __syncthreads();
        #pragma unroll
        for (int kp = 0; kp < 16; ++kp) {
            float2 xv[4], wv[4];
            #pragma unroll
            for (int r = 0; r < 4; ++r) xv[r] = *(const float2*)&Xs[ty * 4 + r][kp * 2];
            #pragma unroll
            for (int q = 0; q < 4; ++q) wv[q] = *(const float2*)&Ws[tx + 32 * q][kp * 2];
            #pragma unroll
            for (int r = 0; r < 4; ++r)
                #pragma unroll
                for (int q = 0; q < 4; ++q)
                    acc[r][q] += xv[r].x * wv[q].x + xv[r].y * wv[q].y;
        }
        __syncthreads();
    }

    float ps[4] = { 0.f, 0.f, 0.f, 0.f };
    #pragma unroll
    for (int q = 0; q < 4; ++q) {
        int c2 = tx + 32 * q;
        float b = brel[c2];
        #pragma unroll
        for (int r = 0; r < 4; ++r) {
            int jg = jb + ty * 4 + r;
            if (jg < n) {
                float v = fmaxf(acc[r][q] + b, 0.0f);
                h_out[((size_t)g * n + jg) * 128 + c2] = v;
                ps[q] += v;
            }
        }
    }
    float* red = &Ws[0][0];
    #pragma unroll
    for (int q = 0; q < 4; ++q) red[ty * 128 + tx + 32 * q] = ps[q];
    __syncthreads();
    if (tid < 128) {
        float s = 0.f;
        #pragma unroll
        for (int t = 0; t < 8; ++t) s += red[t * 128 + tid];
        atomicAdd(&xs[g * 128 + tid], s / (float)n);
    }
}

// ---------------------------------------- pool stage 1: S, masks, deg
__global__ __launch_bounds__(512) void k_pool_S(
    const float* __restrict__ h_in, const u32* __restrict__ Mb_g,
    float* __restrict__ S_cm, u32* __restrict__ Mbd, float* __restrict__ deg_g,
    const float* __restrict__ v_g, const float* __restrict__ c0_g,
    const float* __restrict__ att_w, const float* __restrict__ att_bp,
    int n)
{
    const int C = 128;
    const int g = blockIdx.x;
    const float* hg = h_in + (size_t)g * n * C;
    __shared__ __align__(16) float h_s[128 * 128];
    __shared__ u32 Mb_s[128 * 4];
    __shared__ float v_s[128], qa_s[128], xa_s[128];
    __shared__ float c0_s;
    const int tid = threadIdx.x, lane = tid & 63, wid = tid >> 6;
    const float att_b = att_bp[0];

    for (int idx = tid; idx < n * 32; idx += 512)
        *(float4*)(h_s + idx * 4) = *(const float4*)(hg + idx * 4);
    if (tid < 128) v_s[tid] = v_g[tid];
    if (tid == 128) c0_s = c0_g[0];
    for (int j = tid; j < n; j += 512) {
        u32 w0 = Mb_g[(g * 128 + j) * 4 + 0], w1 = Mb_g[(g * 128 + j) * 4 + 1];
        u32 w2 = Mb_g[(g * 128 + j) * 4 + 2], w3 = Mb_g[(g * 128 + j) * 4 + 3];
        int ww = j >> 5; u32 bit = 1u << (j & 31);     // diagonal
        if (ww == 0) w0 |= bit; else if (ww == 1) w1 |= bit;
        else if (ww == 2) w2 |= bit; else w3 |= bit;
        Mb_s[j * 4 + 0] = w0; Mb_s[j * 4 + 1] = w1;
        Mb_s[j * 4 + 2] = w2; Mb_s[j * 4 + 3] = w3;
        Mbd[(g * 128 + j) * 4 + 0] = w0; Mbd[(g * 128 + j) * 4 + 1] = w1;
        Mbd[(g * 128 + j) * 4 + 2] = w2; Mbd[(g * 128 + j) * 4 + 3] = w3;
        deg_g[g * 128 + j] = (float)(__popc(w0) + __popc(w1) + __popc(w2) + __popc(w3));
    }
    __syncthreads();

    // qa[j] = maskedColMax(h)·v + c0  (wave per column)
    for (int j = wid; j < n; j += 8) {
        const u32* mj = &Mb_s[j * 4];
        float acc = 0.f;
        #pragma unroll
        for (int half = 0; half < 2; ++half) {
            int c = lane + half * 64;
            float m = -1e30f;
            #pragma unroll
            for (int ww = 0; ww < 4; ++ww) {
                u32 u = mj[ww];
                while (u) {
                    int i = (ww << 5) + __ffs(u) - 1; u &= u - 1u;
                    m = fmaxf(m, h_s[i * C + c]);
                }
            }
            acc += m * v_s[c];
        }
        for (int off = 32; off; off >>= 1) acc += __shfl_xor(acc, off);
        if (lane == 0) qa_s[j] = acc + c0_s;
    }
    // xa[i] = h[i]·a_x  (wave per row)
    for (int i = wid; i < n; i += 8) {
        float s = h_s[i * C + lane] * att_w[C + lane]
                + h_s[i * C + 64 + lane] * att_w[C + 64 + lane];
        for (int off = 32; off; off >>= 1) s += __shfl_xor(s, off);
        if (lane == 0) xa_s[i] = s;
    }
    __syncthreads();

    // masked column softmax -> S_cm[g][j][i] (row j = column j of S)
    for (int j = wid; j < n; j += 8) {
        const float qaj = qa_s[j];
        const int i0 = lane, i1 = lane + 64;
        const bool b0 = (i0 < n) && ((Mb_s[j * 4 + (i0 >> 5)] >> (i0 & 31)) & 1u);
        const bool b1 = (i1 < n) && ((Mb_s[j * 4 + (i1 >> 5)] >> (i1 & 31)) & 1u);
        float l0 = -1e30f, l1 = -1e30f;
        if (b0) { float t = xa_s[i0] + qaj + att_b; l0 = (t >= 0.f) ? t : NEG_SLOPE * t; }
        if (b1) { float t = xa_s[i1] + qaj + att_b; l1 = (t >= 0.f) ? t : NEG_SLOPE * t; }
        float m = fmaxf(l0, l1);
        for (int off = 32; off; off >>= 1) m = fmaxf(m, __shfl_xor(m, off));
        float e0 = b0 ? expf(l0 - m) : 0.f;
        float e1 = b1 ? expf(l1 - m) : 0.f;
        float s = e0 + e1;
        for (int off = 32; off; off >>= 1) s += __shfl_xor(s, off);
        float* Sj = S_cm + ((size_t)g * 128 + j) * 128;
        if (i0 < n) Sj[i0] = e0 / s;
        if (i1 < n) Sj[i1] = e1 / s;
    }
}

// ---------------------------------------- pool stage 2: x_new = S_cm @ h
__global__ __launch_bounds__(512) void k_xnew(
    const float* __restrict__ S_cm, const float* __restrict__ h,
    float* __restrict__ xn, int n)
{
    const int g = blockIdx.x;
    int idx = blockIdx.y * 512 + threadIdx.x;
    if (idx >= n * 32) return;
    int j = idx >> 5, c4 = (idx & 31) << 2;
    const float* Sj = S_cm + ((size_t)g * 128 + j) * 128;
    const float* hg = h + (size_t)g * n * 128 + c4;
    float sx = 0.f, sy = 0.f, sz = 0.f, sw = 0.f;
    for (int i = 0; i < n; ++i) {
        float sv = Sj[i];
        float4 hv = *(const float4*)(hg + (size_t)i * 128);
        sx += sv * hv.x; sy += sv * hv.y; sz += sv * hv.z; sw += sv * hv.w;
    }
    float4 o; o.x = sx; o.y = sy; o.z = sz; o.w = sw;
    *(float4*)(xn + ((size_t)g * 128 + j) * 128 + c4) = o;
}

// ------------- pool stage 3: fitness, top-k, h_out, Sselr gathers
__global__ __launch_bounds__(512) void k_fit(
    const float* __restrict__ xn, const u32* __restrict__ Mbd,
    const float* __restrict__ deg_g, const float* __restrict__ S_cm,
    const float* __restrict__ le1_w, const float* __restrict__ le1_bp,
    const float* __restrict__ le2_w, const float* __restrict__ le3_w,
    const float* __restrict__ le3_bp,
    float* __restrict__ h_out, float* __restrict__ Sselr, float* __restrict__ SselrT,
    int n, int k, int kpad)
{
    const int g = blockIdx.x;
    const float* xg = xn + (size_t)g * 128 * 128;
    __shared__ float a_s[128], b_s[128], c3_s[128], fit_s[128];
    __shared__ int perm_s[128];
    const int tid = threadIdx.x, lane = tid & 63, wid = tid >> 6;

    for (int j = wid; j < n; j += 8) {
        float x0 = xg[j * 128 + lane], x1 = xg[j * 128 + 64 + lane];
        float s1 = x0 * le1_w[lane] + x1 * le1_w[64 + lane];
        float s2 = x0 * le2_w[lane] + x1 * le2_w[64 + lane];
        float s3 = x0 * le3_w[lane] + x1 * le3_w[64 + lane];
        for (int off = 32; off; off >>= 1) {
            s1 += __shfl_xor(s1, off);
            s2 += __shfl_xor(s2, off);
            s3 += __shfl_xor(s3, off);
        }
        if (lane == 0) { a_s[j] = s1 + le1_bp[0]; b_s[j] = s2; c3_s[j] = s3; }
    }
    __syncthreads();
    for (int j = tid; j < n; j += 512) {
        const u32* mj = Mbd + (g * 128 + j) * 4;
        float s = 0.f;
        #pragma unroll
        for (int ww = 0; ww < 4; ++ww) {
            u32 u = mj[ww];
            while (u) { int i = (ww << 5) + __ffs(u) - 1; u &= u - 1u; s += a_s[i]; }
        }
        float f = s - deg_g[g * 128 + j] * b_s[j] + c3_s[j] + le3_bp[0];
        fit_s[j] = 1.0f / (1.0f + expf(-f));
    }
    __syncthreads();
    // top-k by rank (ties -> lower index, matches lax.top_k)
    for (int j = tid; j < n; j += 512) {
        float fj = fit_s[j];
        int r = 0;
        for (int j2 = 0; j2 < n; ++j2) {
            float f2 = fit_s[j2];
            if (f2 > fj || (f2 == fj && j2 < j)) ++r;
        }
        if (r < k) perm_s[r] = j;
    }
    __syncthreads();
    // h_out[r] = x_new[perm[r]] * fit[perm[r]]
    for (int idx = tid; idx < k * 32; idx += 512) {
        int r = idx >> 5, c4 = (idx & 31) << 2;
        int p = perm_s[r]; float f = fit_s[p];
        float4 v = *(const float4*)(xg + p * 128 + c4);
        v.x *= f; v.y *= f; v.z *= f; v.w *= f;
        *(float4*)(h_out + ((size_t)g * k + r) * 128 + c4) = v;
    }
    // SselrT[r][i] = S_cm[perm[r]][i]   (row gather, coalesced)
    for (int idx = tid; idx < k * 32; idx += 512) {
        int r = idx >> 5, c4 = (idx & 31) << 2;
        float4 v = *(const float4*)(S_cm + ((size_t)g * 128 + perm_s[r]) * 128 + c4);
        *(float4*)(SselrT + ((size_t)g * 128 + r) * 128 + c4) = v;
    }
    // Sselr[i][cc] = S_cm[perm[cc]][i]  (coalesced reads, scattered 4B writes)
    for (int idx = tid; idx < k * n; idx += 512) {
        int cc = idx / n, i = idx - cc * n;
        Sselr[((size_t)g * 128 + i) * kpad + cc] =
            S_cm[((size_t)g * 128 + perm_s[cc]) * 128 + i];
    }
}

// ---------------------------------------- pool stage 4: T = A_d @ S_sel
__global__ __launch_bounds__(512) void k_T_mask(
    const u32* __restrict__ Rb, const float* __restrict__ Sselr,
    float* __restrict__ T, int n, int k, int kpad)
{
    const int g = blockIdx.x;
    const int ccq = (k + 3) >> 2;
    int idx = blockIdx.y * 512 + threadIdx.x;
    if (idx >= n * ccq) return;
    int i = idx / ccq, c4 = (idx - i * ccq) << 2;
    u32 m[4];
    m[0] = Rb[(g * 128 + i) * 4 + 0]; m[1] = Rb[(g * 128 + i) * 4 + 1];
    m[2] = Rb[(g * 128 + i) * 4 + 2]; m[3] = Rb[(g * 128 + i) * 4 + 3];
    m[i >> 5] |= 1u << (i & 31);                      // diagonal
    float sx = 0.f, sy = 0.f, sz = 0.f, sw = 0.f;
    #pragma unroll
    for (int ww = 0; ww < 4; ++ww) {
        u32 u = m[ww];
        while (u) {
            int j = (ww << 5) + __ffs(u) - 1; u &= u - 1u;
            float4 v = *(const float4*)(Sselr + ((size_t)g * 128 + j) * kpad + c4);
            sx += v.x; sy += v.y; sz += v.z; sw += v.w;
        }
    }
    float4 o; o.x = sx; o.y = sy; o.z = sz; o.w = sw;
    *(float4*)(T + ((size_t)g * 128 + i) * kpad + c4) = o;
}

__global__ __launch_bounds__(512) void k_T_dense(
    const float* __restrict__ A, const float* __restrict__ Sselr,
    float* __restrict__ T, int n, int k, int kpad)
{
    const int g = blockIdx.x;
    const int ccq = (k + 3) >> 2;
    int idx = blockIdx.y * 512 + threadIdx.x;
    if (idx >= n * ccq) return;
    int i = idx / ccq, c4 = (idx - i * ccq) << 2;
    const float* Ai = A + ((size_t)g * n + i) * n;    // unit diag already present
    float sx = 0.f, sy = 0.f, sz = 0.f, sw = 0.f;
    for (int j = 0; j < n; ++j) {
        float a = Ai[j];
        float4 v = *(const float4*)(Sselr + ((size_t)g * 128 + j) * kpad + c4);
        sx += a * v.x; sy += a * v.y; sz += a * v.z; sw += a * v.w;
    }
    float4 o; o.x = sx; o.y = sy; o.z = sz; o.w = sw;
    *(float4*)(T + ((size_t)g * 128 + i) * kpad + c4) = o;
}

// ------------- pool stage 5: A2 = S_sel^T @ T (+diag, +transpose, +mask)
__global__ __launch_bounds__(512) void k_A2(
    const float* __restrict__ SselrT, const float* __restrict__ T,
    float* __restrict__ A_out, float* __restrict__ AT_out,
    u32* __restrict__ Mb_out, int n, int k, int kpad)
{
    const int g = blockIdx.x;
    int idx = blockIdx.y * 512 + threadIdx.x;
    if (idx >= k * k) return;
    int r = idx / k, cc = idx - r * k;
    const float* Sr = SselrT + ((size_t)g * 128 + r) * 128;
    const float* Tg = T + (size_t)g * 128 * kpad;
    float s = 0.f;
    for (int i = 0; i < n; ++i) s += Sr[i] * Tg[i * kpad + cc];
    float val = (r == cc) ? 1.0f : s;
    A_out[((size_t)g * k + r) * k + cc] = val;
    AT_out[((size_t)g * k + cc) * k + r] = val;
    if (val != 0.0f)
        atomicOr(&Mb_out[((size_t)g * 128 + cc) * 4 + (r >> 5)], 1u << (r & 31));
}

// ------------------------------------------------------------- classifier ---
// one block per group; wave per output column; coalesced w1 reads
__global__ __launch_bounds__(256) void k_final(
    const float* __restrict__ xs,     // [5][16][128]
    const float* __restrict__ w1, const float* __restrict__ b1,
    const float* __restrict__ w2, const float* __restrict__ b2,
    float* __restrict__ out)
{
    const int g = blockIdx.x;
    __shared__ float j_s[640];
    __shared__ float z1[128];
    const int tid = threadIdx.x, lane = tid & 63, wid = tid >> 6;  // 4 waves

    for (int idx = tid; idx < 640; idx += 256) {
        int t = idx >> 7, c = idx & 127;
        j_s[idx] = xs[t * 2048 + g * 128 + c];
    }
    __syncthreads();
    for (int c2 = wid; c2 < 128; c2 += 4) {
        const float* wrow = w1 + (size_t)c2 * 640;
        float s = 0.f;
        #pragma unroll
        for (int it = 0; it < 10; ++it) {
            int kk = it * 64 + lane;
            s += j_s[kk] * wrow[kk];
        }
        for (int off = 32; off; off >>= 1) s += __shfl_xor(s, off);
        if (lane == 0) z1[c2] = fmaxf(s + b1[c2], 0.0f);
    }
    __syncthreads();
    if (wid == 0) {
        float zv0 = z1[lane], zv1 = z1[lane + 64];
        float za = zv0 * w2[lane] + zv1 * w2[lane + 64];
        float zb = zv0 * w2[128 + lane] + zv1 * w2[192 + lane];
        for (int off = 32; off; off >>= 1) {
            za += __shfl_xor(za, off);
            zb += __shfl_xor(zb, off);
        }
        if (lane == 0) {
            za += b2[0]; zb += b2[1];
            float m = fmaxf(za, zb);
            float lse = m + logf(expf(za - m) + expf(zb - m));
            out[g * 2 + 0] = za - lse;
            out[g * 2 + 1] = zb - lse;
        }
    }
}

// ---------------------------------------------------------------------------
extern "C" void kernel_launch(void* const* d_in, const int* in_sizes, int n_in,
                              void* d_out, int out_size, void* d_ws, size_t ws_size,
                              hipStream_t stream)
{
    (void)n_in; (void)out_size; (void)ws_size;
    const float* x        = (const float*)d_in[0];
    const int*   ei       = (const int*)  d_in[1];
    const float* c0_wrel  = (const float*)d_in[2];
    const float* c0_brel  = (const float*)d_in[3];
    const float* c0_wroot = (const float*)d_in[4];
    const float* cw_rel   = (const float*)d_in[5];
    const float* cb_rel   = (const float*)d_in[6];
    const float* cw_root  = (const float*)d_in[7];
    const float* p_lin_w  = (const float*)d_in[8];
    const float* p_lin_b  = (const float*)d_in[9];
    const float* p_att_w  = (const float*)d_in[10];
    const float* p_att_b  = (const float*)d_in[11];
    const float* p_le1_w  = (const float*)d_in[12];
    const float* p_le1_b  = (const float*)d_in[13];
    const float* p_le2_w  = (const float*)d_in[14];
    const float* p_le3_w  = (const float*)d_in[15];
    const float* p_le3_b  = (const float*)d_in[16];
    const float* lin1_w   = (const float*)d_in[17];
    const float* lin1_b   = (const float*)d_in[18];
    const float* lin2_w   = (const float*)d_in[19];
    const float* lin2_b   = (const float*)d_in[20];
    float* out = (float*)d_out;

    const int E = in_sizes[1] / 2;   // 32768

    // workspace layout (memset region first: Mb1|Rb1|xsf|Mb2|Mb3)
    u32*   Mb1 = (u32*)d_ws;                  //  8192
    u32*   Rb1 = Mb1 + 8192;                  //  8192
    float* xsf = (float*)(Rb1 + 8192);        // 10240
    u32*   Mb2 = (u32*)(xsf + 10240);         //  8192
    u32*   Mb3 = Mb2 + 8192;                  //  8192
    u32*   Mbd = Mb3 + 8192;                  //  8192
    float* degw = (float*)(Mbd + 8192);       //  2048
    float* vbuf = degw + 2048;                //  256 (2 x 128)
    float* c0buf = vbuf + 256;                //  2 (+pad 2)
    float* agg = c0buf + 4;                   // 262144 (aliased as T_ws in pools)
    float* hA  = agg + 262144;                // 262144
    float* hB  = hA  + 262144;                // 262144
    float* Scm = hB  + 262144;                // 262144
    float* xnw = Scm + 262144;                // 262144
    float* Ssr = xnw + 262144;                // 16*128*112 = 229376
    float* SsT = Ssr + 229376;                // 262144
    float* A2  = SsT + 262144;                // 169744
    float* A2T = A2  + 169744;                // 169744
    float* A3  = A2T + 169744;                // 110224
    float* A3T = A3  + 110224;                // 110224
    float* Tw  = agg;                         // alias: disjoint lifetime vs conv agg

    hipMemsetAsync(d_ws, 0, (8192 + 8192 + 10240 + 8192 + 8192) * 4, stream);
    k_build<<<(E + 255) / 256, 256, 0, stream>>>(ei, Mb1, Rb1, E);
    k_prep<<<2, 128, 0, stream>>>(p_lin_w, p_lin_b, p_att_w, vbuf, c0buf);

    // conv0: Cin=64
    k_agg_mask<<<dim3(16, 4), 512, 0, stream>>>(x, Mb1, agg, 128, 64);
    k_out<<<dim3(16, 4), 256, 0, stream>>>(x, agg, c0_wrel, c0_brel, c0_wroot,
                                           hA, xsf + 0 * 2048, 128, 64);
    // conv1
    k_agg_mask<<<dim3(16, 8), 512, 0, stream>>>(hA, Mb1, agg, 128, 128);
    k_out<<<dim3(16, 4), 256, 0, stream>>>(hA, agg, cw_rel, cb_rel, cw_root,
                                           hB, xsf + 1 * 2048, 128, 128);
    // pool1: n=128 -> k=103 (kpad=112)
    k_pool_S<<<16, 512, 0, stream>>>(hB, Mb1, Scm, Mbd, degw,
                                     vbuf, c0buf, p_att_w, p_att_b, 128);
    k_xnew<<<dim3(16, 8), 512, 0, stream>>>(Scm, hB, xnw, 128);
    k_fit<<<16, 512, 0, stream>>>(xnw, Mbd, degw, Scm,
                                  p_le1_w, p_le1_b, p_le2_w, p_le3_w, p_le3_b,
                                  hA, Ssr, SsT, 128, 103, 112);
    k_T_mask<<<dim3(16, 7), 512, 0, stream>>>(Rb1, Ssr, Tw, 128, 103, 112);
    k_A2<<<dim3(16, 21), 512, 0, stream>>>(SsT, Tw, A2, A2T, Mb2, 128, 103, 112);
    // conv2
    k_agg_dense<<<dim3(16, 7), 512, 0, stream>>>(hA, A2T, Mb2, agg, 103);
    k_out<<<dim3(16, 4), 256, 0, stream>>>(hA, agg, cw_rel + 16384, cb_rel + 128,
                                           cw_root + 16384, hB, xsf + 2 * 2048, 103, 128);
    // conv3
    k_agg_dense<<<dim3(16, 7), 512, 0, stream>>>(hB, A2T, Mb2, agg, 103);
    k_out<<<dim3(16, 4), 256, 0, stream>>>(hB, agg, cw_rel + 2 * 16384, cb_rel + 2 * 128,
                                           cw_root + 2 * 16384, hA, xsf + 3 * 2048, 103, 128);
    // pool2: n=103 -> k=83 (kpad=96)
    k_pool_S<<<16, 512, 0, stream>>>(hA, Mb2, Scm, Mbd, degw,
                                     vbuf + 128, c0buf + 1, p_att_w + 256, p_att_b + 1, 103);
    k_xnew<<<dim3(16, 7), 512, 0, stream>>>(Scm, hA, xnw, 103);
    k_fit<<<16, 512, 0, stream>>>(xnw, Mbd, degw, Scm,
                                  p_le1_w + 128, p_le1_b + 1, p_le2_w + 128,
                                  p_le3_w + 128, p_le3_b + 1,
                                  hB, Ssr, SsT, 103, 83, 96);
    k_T_dense<<<dim3(16, 5), 512, 0, stream>>>(A2, Ssr, Tw, 103, 83, 96);
    k_A2<<<dim3(16, 14), 512, 0, stream>>>(SsT, Tw, A3, A3T, Mb3, 103, 83, 96);
    // conv4
    k_agg_dense<<<dim3(16, 6), 512, 0, stream>>>(hB, A3T, Mb3, agg, 83);
    k_out<<<dim3(16, 3), 256, 0, stream>>>(hB, agg, cw_rel + 3 * 16384, cb_rel + 3 * 128,
                                           cw_root + 3 * 16384, hA, xsf + 4 * 2048, 83, 128);

    k_final<<<16, 256, 0, stream>>>(xsf, lin1_w, lin1_b, lin2_w, lin2_b, out);
}

// Round 5
// 586.498 us; speedup vs baseline: 7.4783x; 1.3124x over previous
//
#include <hip/hip_runtime.h>

#define NEG_SLOPE 0.2f
typedef unsigned int u32;

// ------------------------------------------------------------ build bitmasks
__global__ __launch_bounds__(256) void k_build(const int* __restrict__ ei,
                                               u32* __restrict__ Mb,
                                               u32* __restrict__ Rb, int E)
{
    int e = blockIdx.x * 256 + threadIdx.x;
    if (e >= E) return;
    int s = ei[e], d = ei[E + e];
    int g = s >> 7, ls = s & 127, ld = d & 127;
    atomicOr(&Mb[(g * 128 + ld) * 4 + (ls >> 5)], 1u << (ls & 31));  // col mask (in-edges)
    atomicOr(&Rb[(g * 128 + ls) * 4 + (ld >> 5)], 1u << (ld & 31));  // row mask (out-edges)
}

// ------------------------------------- precompute v = lin_w^T a_q, c0 = lin_b·a_q
__global__ __launch_bounds__(128) void k_prep(
    const float* __restrict__ lin_w, const float* __restrict__ lin_b,
    const float* __restrict__ att_w,
    float* __restrict__ v_out, float* __restrict__ c0_out)
{
    const int p = blockIdx.x;
    const float* lw = lin_w + p * 16384;
    const float* lb = lin_b + p * 128;
    const float* aw = att_w + p * 256;
    const int c = threadIdx.x;
    float s = 0.f;
    for (int c2 = 0; c2 < 128; ++c2) s += aw[c2] * lw[c2 * 128 + c];
    v_out[p * 128 + c] = s;
    if (c < 64) {
        float s0 = aw[c] * lb[c] + aw[c + 64] * lb[c + 64];
        for (int off = 32; off; off >>= 1) s0 += __shfl_xor(s0, off);
        if (c == 0) c0_out[p] = s0;
    }
}

// --------------------------------------------- agg = (A^T h)/deg, binary A
__global__ __launch_bounds__(512) void k_agg_mask(
    const float* __restrict__ h, const u32* __restrict__ Mb,
    float* __restrict__ agg, int n, int Cin)
{
    const int g = blockIdx.x;
    const int q4 = Cin >> 2;
    int idx = blockIdx.y * 512 + threadIdx.x;
    if (idx >= n * q4) return;
    int j = idx / q4, c4 = (idx - j * q4) << 2;
    const u32* m = Mb + (g * 128 + j) * 4;
    u32 m0 = m[0], m1 = m[1], m2 = m[2], m3 = m[3];
    float dv = fmaxf((float)(__popc(m0) + __popc(m1) + __popc(m2) + __popc(m3)), 1.0f);
    const float* hg = h + (size_t)g * n * Cin + c4;
    float sx = 0.f, sy = 0.f, sz = 0.f, sw = 0.f;
    u32 wds[4] = { m0, m1, m2, m3 };
    #pragma unroll
    for (int ww = 0; ww < 4; ++ww) {
        u32 u = wds[ww];
        while (u) {
            int i = (ww << 5) + __ffs(u) - 1; u &= u - 1u;
            float4 hv = *(const float4*)(hg + (size_t)i * Cin);
            sx += hv.x; sy += hv.y; sz += hv.z; sw += hv.w;
        }
    }
    float4 o; o.x = sx / dv; o.y = sy / dv; o.z = sz / dv; o.w = sw / dv;
    *(float4*)(agg + ((size_t)g * n + j) * Cin + c4) = o;
}

// --------------------------------------------- agg = (A^T h)/deg, dense A via A^T
__global__ __launch_bounds__(512) void k_agg_dense(
    const float* __restrict__ h, const float* __restrict__ AT,
    const u32* __restrict__ Mb, float* __restrict__ agg, int n)
{
    const int C = 128;
    const int g = blockIdx.x;
    int idx = blockIdx.y * 512 + threadIdx.x;
    if (idx >= n * 32) return;
    int j = idx >> 5, c4 = (idx & 31) << 2;
    const u32* m = Mb + (g * 128 + j) * 4;
    float dv = fmaxf((float)(__popc(m[0]) + __popc(m[1]) + __popc(m[2]) + __popc(m[3])), 1.0f);
    const float* Aj = AT + ((size_t)g * n + j) * n;     // AT[j][i] = A[i][j]
    const float* hg = h + (size_t)g * n * C + c4;
    float sx = 0.f, sy = 0.f, sz = 0.f, sw = 0.f;
    for (int i = 0; i < n; ++i) {
        float a = Aj[i];
        float4 hv = *(const float4*)(hg + (size_t)i * C);
        sx += a * hv.x; sy += a * hv.y; sz += a * hv.z; sw += a * hv.w;
    }
    float4 o; o.x = sx / dv; o.y = sy / dv; o.z = sz / dv; o.w = sw / dv;
    *(float4*)(agg + ((size_t)g * n + j) * C + c4) = o;
}

// ------- out = relu(agg@wrel^T + brel + h@wroot^T), fused gpool partial sums
__global__ __launch_bounds__(256) void k_out(
    const float* __restrict__ h, const float* __restrict__ agg,
    const float* __restrict__ wrel, const float* __restrict__ brel,
    const float* __restrict__ wroot,
    float* __restrict__ h_out, float* __restrict__ xs,
    int n, int Cin)
{
    const int g = blockIdx.x;
    const int jb = blockIdx.y * 32;
    const int tid = threadIdx.x;
    const int tx = tid & 31, ty = tid >> 5;            // ty 0..7
    __shared__ float Xs[32][34];
    __shared__ float Ws[128][34];
    float acc[4][4] = {};
    const int K = 2 * Cin;
    const float* hg = h + (size_t)g * n * Cin;
    const float* ag = agg + (size_t)g * n * Cin;

    for (int kk = 0; kk < K; kk += 32) {
        const float* Xsrc = (kk < Cin) ? (ag + kk) : (hg + kk - Cin);
        #pragma unroll
        for (int it = 0; it < 2; ++it) {
            int l = it * 256 + tid;
            int kp = l & 15, j = l >> 4;
            int jg = jb + j; if (jg > n - 1) jg = n - 1;
            float2 v = *(const float2*)(Xsrc + (size_t)jg * Cin + kp * 2);
            *(float2*)&Xs[j][kp * 2] = v;
        }
        const float* Wsrc = (kk < Cin) ? (wrel + kk) : (wroot + kk - Cin);
        #pragma unroll
        for (int it = 0; it < 8; ++it) {
            int l = it * 256 + tid;
            int kp = l & 15, c2 = l >> 4;
            float2 v = *(const float2*)(Wsrc + (size_t)c2 * Cin + kp * 2);
            *(float2*)&Ws[c2][kp * 2] = v;
        }
        __syncthreads();
        #pragma unroll
        for (int kp = 0; kp < 16; ++kp) {
            float2 xv[4], wv[4];
            #pragma unroll
            for (int r = 0; r < 4; ++r) xv[r] = *(const float2*)&Xs[ty * 4 + r][kp * 2];
            #pragma unroll
            for (int q = 0; q < 4; ++q) wv[q] = *(const float2*)&Ws[tx + 32 * q][kp * 2];
            #pragma unroll
            for (int r = 0; r < 4; ++r)
                #pragma unroll
                for (int q = 0; q < 4; ++q)
                    acc[r][q] += xv[r].x * wv[q].x + xv[r].y * wv[q].y;
        }
        __syncthreads();
    }

    float ps[4] = { 0.f, 0.f, 0.f, 0.f };
    #pragma unroll
    for (int q = 0; q < 4; ++q) {
        int c2 = tx + 32 * q;
        float b = brel[c2];
        #pragma unroll
        for (int r = 0; r < 4; ++r) {
            int jg = jb + ty * 4 + r;
            if (jg < n) {
                float v = fmaxf(acc[r][q] + b, 0.0f);
                h_out[((size_t)g * n + jg) * 128 + c2] = v;
                ps[q] += v;
            }
        }
    }
    float* red = &Ws[0][0];
    #pragma unroll
    for (int q = 0; q < 4; ++q) red[ty * 128 + tx + 32 * q] = ps[q];
    __syncthreads();
    if (tid < 128) {
        float s = 0.f;
        #pragma unroll
        for (int t = 0; t < 8; ++t) s += red[t * 128 + tid];
        atomicAdd(&xs[g * 128 + tid], s / (float)n);
    }
}

// ------------- pool stage 1a: qa[j] = maskedColMax(h)·v + c0 ; xa[i] = h[i]·a_x
// half-wave (32 lanes) per column/row; lane owns 4 channels; L2 float4 reads
__global__ __launch_bounds__(512) void k_attn(
    const float* __restrict__ h, const u32* __restrict__ Mb_g,
    const float* __restrict__ v_g, const float* __restrict__ c0_g,
    const float* __restrict__ att_w,
    float* __restrict__ qa_g, float* __restrict__ xa_g, int n)
{
    const int g = blockIdx.x;
    const int tid = threadIdx.x;
    const int hw = tid >> 5, ln = tid & 31;
    const float* hg = h + (size_t)g * n * 128;
    const int j = blockIdx.y * 16 + hw;
    if (j < n) {
        u32 m[4];
        m[0] = Mb_g[(g * 128 + j) * 4 + 0]; m[1] = Mb_g[(g * 128 + j) * 4 + 1];
        m[2] = Mb_g[(g * 128 + j) * 4 + 2]; m[3] = Mb_g[(g * 128 + j) * 4 + 3];
        m[j >> 5] |= 1u << (j & 31);                  // diagonal
        float4 mx = make_float4(-1e30f, -1e30f, -1e30f, -1e30f);
        #pragma unroll
        for (int ww = 0; ww < 4; ++ww) {
            u32 u = m[ww];
            while (u) {
                int i = (ww << 5) + __ffs(u) - 1; u &= u - 1u;
                float4 hv = *(const float4*)(hg + (size_t)i * 128 + ln * 4);
                mx.x = fmaxf(mx.x, hv.x); mx.y = fmaxf(mx.y, hv.y);
                mx.z = fmaxf(mx.z, hv.z); mx.w = fmaxf(mx.w, hv.w);
            }
        }
        float4 vv = *(const float4*)(v_g + ln * 4);
        float acc = mx.x * vv.x + mx.y * vv.y + mx.z * vv.z + mx.w * vv.w;
        #pragma unroll
        for (int off = 16; off; off >>= 1) acc += __shfl_xor(acc, off, 32);
        if (ln == 0) qa_g[g * 128 + j] = acc + c0_g[0];
    }
    const int i = blockIdx.y * 16 + hw;
    if (i < n) {
        float4 hv = *(const float4*)(hg + (size_t)i * 128 + ln * 4);
        float4 aw = *(const float4*)(att_w + 128 + ln * 4);
        float s = hv.x * aw.x + hv.y * aw.y + hv.z * aw.z + hv.w * aw.w;
        #pragma unroll
        for (int off = 16; off; off >>= 1) s += __shfl_xor(s, off, 32);
        if (ln == 0) xa_g[g * 128 + i] = s;
    }
}

// ------------- pool stage 1b: masked column softmax -> S_cm (wave per column)
__global__ __launch_bounds__(512) void k_soft(
    const u32* __restrict__ Mb_g, const float* __restrict__ qa_g,
    const float* __restrict__ xa_g, const float* __restrict__ att_bp,
    float* __restrict__ S_cm, int n)
{
    const int g = blockIdx.x;
    const int tid = threadIdx.x, lane = tid & 63, wid = tid >> 6;
    const int j = blockIdx.y * 8 + wid;
    if (j >= n) return;
    const float att_b = att_bp[0];
    u32 m[4];
    m[0] = Mb_g[(g * 128 + j) * 4 + 0]; m[1] = Mb_g[(g * 128 + j) * 4 + 1];
    m[2] = Mb_g[(g * 128 + j) * 4 + 2]; m[3] = Mb_g[(g * 128 + j) * 4 + 3];
    m[j >> 5] |= 1u << (j & 31);                      // diagonal
    const float qaj = qa_g[g * 128 + j];
    const int i0 = lane, i1 = lane + 64;
    const bool b0 = (i0 < n) && ((m[i0 >> 5] >> (i0 & 31)) & 1u);
    const bool b1 = (i1 < n) && ((m[i1 >> 5] >> (i1 & 31)) & 1u);
    float l0 = -1e30f, l1 = -1e30f;
    if (b0) { float t = xa_g[g * 128 + i0] + qaj + att_b; l0 = (t >= 0.f) ? t : NEG_SLOPE * t; }
    if (b1) { float t = xa_g[g * 128 + i1] + qaj + att_b; l1 = (t >= 0.f) ? t : NEG_SLOPE * t; }
    float mm = fmaxf(l0, l1);
    for (int off = 32; off; off >>= 1) mm = fmaxf(mm, __shfl_xor(mm, off));
    float e0 = b0 ? expf(l0 - mm) : 0.f;
    float e1 = b1 ? expf(l1 - mm) : 0.f;
    float s = e0 + e1;
    for (int off = 32; off; off >>= 1) s += __shfl_xor(s, off);
    float* Sj = S_cm + ((size_t)g * 128 + j) * 128;
    if (i0 < n) Sj[i0] = e0 / s;
    if (i1 < n) Sj[i1] = e1 / s;
}

// ---------------------------------------- pool stage 2: x_new = S_cm @ h
__global__ __launch_bounds__(512) void k_xnew(
    const float* __restrict__ S_cm, const float* __restrict__ h,
    float* __restrict__ xn, int n)
{
    const int g = blockIdx.x;
    int idx = blockIdx.y * 512 + threadIdx.x;
    if (idx >= n * 32) return;
    int j = idx >> 5, c4 = (idx & 31) << 2;
    const float* Sj = S_cm + ((size_t)g * 128 + j) * 128;
    const float* hg = h + (size_t)g * n * 128 + c4;
    float sx = 0.f, sy = 0.f, sz = 0.f, sw = 0.f;
    for (int i = 0; i < n; ++i) {
        float sv = Sj[i];
        float4 hv = *(const float4*)(hg + (size_t)i * 128);
        sx += sv * hv.x; sy += sv * hv.y; sz += sv * hv.z; sw += sv * hv.w;
    }
    float4 o; o.x = sx; o.y = sy; o.z = sz; o.w = sw;
    *(float4*)(xn + ((size_t)g * 128 + j) * 128 + c4) = o;
}

// ------------- pool stage 3: fitness, top-k, h_out, Sselr gathers
__global__ __launch_bounds__(512) void k_fit(
    const float* __restrict__ xn, const u32* __restrict__ Mb_g,
    const float* __restrict__ S_cm,
    const float* __restrict__ le1_w, const float* __restrict__ le1_bp,
    const float* __restrict__ le2_w, const float* __restrict__ le3_w,
    const float* __restrict__ le3_bp,
    float* __restrict__ h_out, float* __restrict__ Sselr, float* __restrict__ SselrT,
    int n, int k, int kpad)
{
    const int g = blockIdx.x;
    const float* xg = xn + (size_t)g * 128 * 128;
    __shared__ float a_s[128], b_s[128], c3_s[128], fit_s[128];
    __shared__ int perm_s[128];
    const int tid = threadIdx.x, lane = tid & 63, wid = tid >> 6;

    for (int j = wid; j < n; j += 8) {
        float x0 = xg[j * 128 + lane], x1 = xg[j * 128 + 64 + lane];
        float s1 = x0 * le1_w[lane] + x1 * le1_w[64 + lane];
        float s2 = x0 * le2_w[lane] + x1 * le2_w[64 + lane];
        float s3 = x0 * le3_w[lane] + x1 * le3_w[64 + lane];
        for (int off = 32; off; off >>= 1) {
            s1 += __shfl_xor(s1, off);
            s2 += __shfl_xor(s2, off);
            s3 += __shfl_xor(s3, off);
        }
        if (lane == 0) { a_s[j] = s1 + le1_bp[0]; b_s[j] = s2; c3_s[j] = s3; }
    }
    __syncthreads();
    for (int j = tid; j < n; j += 512) {
        u32 m[4];
        m[0] = Mb_g[(g * 128 + j) * 4 + 0]; m[1] = Mb_g[(g * 128 + j) * 4 + 1];
        m[2] = Mb_g[(g * 128 + j) * 4 + 2]; m[3] = Mb_g[(g * 128 + j) * 4 + 3];
        m[j >> 5] |= 1u << (j & 31);                  // diagonal
        float dv = (float)(__popc(m[0]) + __popc(m[1]) + __popc(m[2]) + __popc(m[3]));
        float s = 0.f;
        #pragma unroll
        for (int ww = 0; ww < 4; ++ww) {
            u32 u = m[ww];
            while (u) { int i = (ww << 5) + __ffs(u) - 1; u &= u - 1u; s += a_s[i]; }
        }
        float f = s - dv * b_s[j] + c3_s[j] + le3_bp[0];
        fit_s[j] = 1.0f / (1.0f + expf(-f));
    }
    __syncthreads();
    // top-k by rank (ties -> lower index, matches lax.top_k)
    for (int j = tid; j < n; j += 512) {
        float fj = fit_s[j];
        int r = 0;
        for (int j2 = 0; j2 < n; ++j2) {
            float f2 = fit_s[j2];
            if (f2 > fj || (f2 == fj && j2 < j)) ++r;
        }
        if (r < k) perm_s[r] = j;
    }
    __syncthreads();
    // h_out[r] = x_new[perm[r]] * fit[perm[r]]
    for (int idx = tid; idx < k * 32; idx += 512) {
        int r = idx >> 5, c4 = (idx & 31) << 2;
        int p = perm_s[r]; float f = fit_s[p];
        float4 v = *(const float4*)(xg + p * 128 + c4);
        v.x *= f; v.y *= f; v.z *= f; v.w *= f;
        *(float4*)(h_out + ((size_t)g * k + r) * 128 + c4) = v;
    }
    // SselrT[r][i] = S_cm[perm[r]][i]   (row gather, coalesced)
    for (int idx = tid; idx < k * 32; idx += 512) {
        int r = idx >> 5, c4 = (idx & 31) << 2;
        float4 v = *(const float4*)(S_cm + ((size_t)g * 128 + perm_s[r]) * 128 + c4);
        *(float4*)(SselrT + ((size_t)g * 128 + r) * 128 + c4) = v;
    }
    // Sselr[i][cc] = S_cm[perm[cc]][i]  (coalesced reads, scattered 4B writes)
    for (int idx = tid; idx < k * n; idx += 512) {
        int cc = idx / n, i = idx - cc * n;
        Sselr[((size_t)g * 128 + i) * kpad + cc] =
            S_cm[((size_t)g * 128 + perm_s[cc]) * 128 + i];
    }
}

// ---------------------------------------- pool stage 4: T = A_d @ S_sel
__global__ __launch_bounds__(512) void k_T_mask(
    const u32* __restrict__ Rb, const float* __restrict__ Sselr,
    float* __restrict__ T, int n, int k, int kpad)
{
    const int g = blockIdx.x;
    const int ccq = (k + 3) >> 2;
    int idx = blockIdx.y * 512 + threadIdx.x;
    if (idx >= n * ccq) return;
    int i = idx / ccq, c4 = (idx - i * ccq) << 2;
    u32 m[4];
    m[0] = Rb[(g * 128 + i) * 4 + 0]; m[1] = Rb[(g * 128 + i) * 4 + 1];
    m[2] = Rb[(g * 128 + i) * 4 + 2]; m[3] = Rb[(g * 128 + i) * 4 + 3];
    m[i >> 5] |= 1u << (i & 31);                      // diagonal
    float sx = 0.f, sy = 0.f, sz = 0.f, sw = 0.f;
    #pragma unroll
    for (int ww = 0; ww < 4; ++ww) {
        u32 u = m[ww];
        while (u) {
            int j = (ww << 5) + __ffs(u) - 1; u &= u - 1u;
            float4 v = *(const float4*)(Sselr + ((size_t)g * 128 + j) * kpad + c4);
            sx += v.x; sy += v.y; sz += v.z; sw += v.w;
        }
    }
    float4 o; o.x = sx; o.y = sy; o.z = sz; o.w = sw;
    *(float4*)(T + ((size_t)g * 128 + i) * kpad + c4) = o;
}

__global__ __launch_bounds__(512) void k_T_dense(
    const float* __restrict__ A, const float* __restrict__ Sselr,
    float* __restrict__ T, int n, int k, int kpad)
{
    const int g = blockIdx.x;
    const int ccq = (k + 3) >> 2;
    int idx = blockIdx.y * 512 + threadIdx.x;
    if (idx >= n * ccq) return;
    int i = idx / ccq, c4 = (idx - i * ccq) << 2;
    const float* Ai = A + ((size_t)g * n + i) * n;    // unit diag already present
    float sx = 0.f, sy = 0.f, sz = 0.f, sw = 0.f;
    for (int j = 0; j < n; ++j) {
        float a = Ai[j];
        float4 v = *(const float4*)(Sselr + ((size_t)g * 128 + j) * kpad + c4);
        sx += a * v.x; sy += a * v.y; sz += a * v.z; sw += a * v.w;
    }
    float4 o; o.x = sx; o.y = sy; o.z = sz; o.w = sw;
    *(float4*)(T + ((size_t)g * 128 + i) * kpad + c4) = o;
}

// ------------- pool stage 5: A2 = S_sel^T @ T (+diag, +transpose, +mask)
__global__ __launch_bounds__(512) void k_A2(
    const float* __restrict__ SselrT, const float* __restrict__ T,
    float* __restrict__ A_out, float* __restrict__ AT_out,
    u32* __restrict__ Mb_out, int n, int k, int kpad)
{
    const int g = blockIdx.x;
    int idx = blockIdx.y * 512 + threadIdx.x;
    if (idx >= k * k) return;
    int r = idx / k, cc = idx - r * k;
    const float* Sr = SselrT + ((size_t)g * 128 + r) * 128;
    const float* Tg = T + (size_t)g * 128 * kpad;
    float s = 0.f;
    for (int i = 0; i < n; ++i) s += Sr[i] * Tg[i * kpad + cc];
    float val = (r == cc) ? 1.0f : s;
    A_out[((size_t)g * k + r) * k + cc] = val;
    AT_out[((size_t)g * k + cc) * k + r] = val;
    if (val != 0.0f)
        atomicOr(&Mb_out[((size_t)g * 128 + cc) * 4 + (r >> 5)], 1u << (r & 31));
}

// ------------------------------------------------------------- classifier ---
__global__ __launch_bounds__(256) void k_final(
    const float* __restrict__ xs,     // [5][16][128]
    const float* __restrict__ w1, const float* __restrict__ b1,
    const float* __restrict__ w2, const float* __restrict__ b2,
    float* __restrict__ out)
{
    const int g = blockIdx.x;
    __shared__ float j_s[640];
    __shared__ float z1[128];
    const int tid = threadIdx.x, lane = tid & 63, wid = tid >> 6;  // 4 waves

    for (int idx = tid; idx < 640; idx += 256) {
        int t = idx >> 7, c = idx & 127;
        j_s[idx] = xs[t * 2048 + g * 128 + c];
    }
    __syncthreads();
    for (int c2 = wid; c2 < 128; c2 += 4) {
        const float* wrow = w1 + (size_t)c2 * 640;
        float s = 0.f;
        #pragma unroll
        for (int it = 0; it < 10; ++it) {
            int kk = it * 64 + lane;
            s += j_s[kk] * wrow[kk];
        }
        for (int off = 32; off; off >>= 1) s += __shfl_xor(s, off);
        if (lane == 0) z1[c2] = fmaxf(s + b1[c2], 0.0f);
    }
    __syncthreads();
    if (wid == 0) {
        float zv0 = z1[lane], zv1 = z1[lane + 64];
        float za = zv0 * w2[lane] + zv1 * w2[lane + 64];
        float zb = zv0 * w2[128 + lane] + zv1 * w2[192 + lane];
        for (int off = 32; off; off >>= 1) {
            za += __shfl_xor(za, off);
            zb += __shfl_xor(zb, off);
        }
        if (lane == 0) {
            za += b2[0]; zb += b2[1];
            float m = fmaxf(za, zb);
            float lse = m + logf(expf(za - m) + expf(zb - m));
            out[g * 2 + 0] = za - lse;
            out[g * 2 + 1] = zb - lse;
        }
    }
}

// ---------------------------------------------------------------------------
extern "C" void kernel_launch(void* const* d_in, const int* in_sizes, int n_in,
                              void* d_out, int out_size, void* d_ws, size_t ws_size,
                              hipStream_t stream)
{
    (void)n_in; (void)out_size; (void)ws_size;
    const float* x        = (const float*)d_in[0];
    const int*   ei       = (const int*)  d_in[1];
    const float* c0_wrel  = (const float*)d_in[2];
    const float* c0_brel  = (const float*)d_in[3];
    const float* c0_wroot = (const float*)d_in[4];
    const float* cw_rel   = (const float*)d_in[5];
    const float* cb_rel   = (const float*)d_in[6];
    const float* cw_root  = (const float*)d_in[7];
    const float* p_lin_w  = (const float*)d_in[8];
    const float* p_lin_b  = (const float*)d_in[9];
    const float* p_att_w  = (const float*)d_in[10];
    const float* p_att_b  = (const float*)d_in[11];
    const float* p_le1_w  = (const float*)d_in[12];
    const float* p_le1_b  = (const float*)d_in[13];
    const float* p_le2_w  = (const float*)d_in[14];
    const float* p_le3_w  = (const float*)d_in[15];
    const float* p_le3_b  = (const float*)d_in[16];
    const float* lin1_w   = (const float*)d_in[17];
    const float* lin1_b   = (const float*)d_in[18];
    const float* lin2_w   = (const float*)d_in[19];
    const float* lin2_b   = (const float*)d_in[20];
    float* out = (float*)d_out;

    const int E = in_sizes[1] / 2;   // 32768

    // workspace layout (memset region first: Mb1|Rb1|xsf|Mb2|Mb3)
    u32*   Mb1 = (u32*)d_ws;                  //  8192
    u32*   Rb1 = Mb1 + 8192;                  //  8192
    float* xsf = (float*)(Rb1 + 8192);        // 10240
    u32*   Mb2 = (u32*)(xsf + 10240);         //  8192
    u32*   Mb3 = Mb2 + 8192;                  //  8192
    float* qaw = (float*)(Mb3 + 8192);        //  2048
    float* xaw = qaw + 2048;                  //  2048
    float* vbuf = xaw + 2048;                 //  256 (2 x 128)
    float* c0buf = vbuf + 256;                //  2 (+pad 2)
    float* agg = c0buf + 4;                   // 262144 (aliased as T_ws in pools)
    float* hA  = agg + 262144;                // 262144
    float* hB  = hA  + 262144;                // 262144
    float* Scm = hB  + 262144;                // 262144
    float* xnw = Scm + 262144;                // 262144
    float* Ssr = xnw + 262144;                // 16*128*112 = 229376
    float* SsT = Ssr + 229376;                // 262144
    float* A2  = SsT + 262144;                // 169744
    float* A2T = A2  + 169744;                // 169744
    float* A3  = A2T + 169744;                // 110224
    float* A3T = A3  + 110224;                // 110224
    float* Tw  = agg;                         // alias: disjoint lifetime vs conv agg

    hipMemsetAsync(d_ws, 0, (8192 + 8192 + 10240 + 8192 + 8192) * 4, stream);
    k_build<<<(E + 255) / 256, 256, 0, stream>>>(ei, Mb1, Rb1, E);
    k_prep<<<2, 128, 0, stream>>>(p_lin_w, p_lin_b, p_att_w, vbuf, c0buf);

    // conv0: Cin=64
    k_agg_mask<<<dim3(16, 4), 512, 0, stream>>>(x, Mb1, agg, 128, 64);
    k_out<<<dim3(16, 4), 256, 0, stream>>>(x, agg, c0_wrel, c0_brel, c0_wroot,
                                           hA, xsf + 0 * 2048, 128, 64);
    // conv1
    k_agg_mask<<<dim3(16, 8), 512, 0, stream>>>(hA, Mb1, agg, 128, 128);
    k_out<<<dim3(16, 4), 256, 0, stream>>>(hA, agg, cw_rel, cb_rel, cw_root,
                                           hB, xsf + 1 * 2048, 128, 128);
    // pool1: n=128 -> k=103 (kpad=112)
    k_attn<<<dim3(16, 8), 512, 0, stream>>>(hB, Mb1, vbuf, c0buf, p_att_w, qaw, xaw, 128);
    k_soft<<<dim3(16, 16), 512, 0, stream>>>(Mb1, qaw, xaw, p_att_b, Scm, 128);
    k_xnew<<<dim3(16, 8), 512, 0, stream>>>(Scm, hB, xnw, 128);
    k_fit<<<16, 512, 0, stream>>>(xnw, Mb1, Scm,
                                  p_le1_w, p_le1_b, p_le2_w, p_le3_w, p_le3_b,
                                  hA, Ssr, SsT, 128, 103, 112);
    k_T_mask<<<dim3(16, 7), 512, 0, stream>>>(Rb1, Ssr, Tw, 128, 103, 112);
    k_A2<<<dim3(16, 21), 512, 0, stream>>>(SsT, Tw, A2, A2T, Mb2, 128, 103, 112);
    // conv2
    k_agg_dense<<<dim3(16, 7), 512, 0, stream>>>(hA, A2T, Mb2, agg, 103);
    k_out<<<dim3(16, 4), 256, 0, stream>>>(hA, agg, cw_rel + 16384, cb_rel + 128,
                                           cw_root + 16384, hB, xsf + 2 * 2048, 103, 128);
    // conv3
    k_agg_dense<<<dim3(16, 7), 512, 0, stream>>>(hB, A2T, Mb2, agg, 103);
    k_out<<<dim3(16, 4), 256, 0, stream>>>(hB, agg, cw_rel + 2 * 16384, cb_rel + 2 * 128,
                                           cw_root + 2 * 16384, hA, xsf + 3 * 2048, 103, 128);
    // pool2: n=103 -> k=83 (kpad=96)
    k_attn<<<dim3(16, 7), 512, 0, stream>>>(hA, Mb2, vbuf + 128, c0buf + 1,
                                            p_att_w + 256, qaw, xaw, 103);
    k_soft<<<dim3(16, 13), 512, 0, stream>>>(Mb2, qaw, xaw, p_att_b + 1, Scm, 103);
    k_xnew<<<dim3(16, 7), 512, 0, stream>>>(Scm, hA, xnw, 103);
    k_fit<<<16, 512, 0, stream>>>(xnw, Mb2, Scm,
                                  p_le1_w + 128, p_le1_b + 1, p_le2_w + 128,
                                  p_le3_w + 128, p_le3_b + 1,
                                  hB, Ssr, SsT, 103, 83, 96);
    k_T_dense<<<dim3(16, 5), 512, 0, stream>>>(A2, Ssr, Tw, 103, 83, 96);
    k_A2<<<dim3(16, 14), 512, 0, stream>>>(SsT, Tw, A3, A3T, Mb3, 103, 83, 96);
    // conv4
    k_agg_dense<<<dim3(16, 6), 512, 0, stream>>>(hB, A3T, Mb3, agg, 83);
    k_out<<<dim3(16, 3), 256, 0, stream>>>(hB, agg, cw_rel + 3 * 16384, cb_rel + 3 * 128,
                                           cw_root + 3 * 16384, hA, xsf + 4 * 2048, 83, 128);

    k_final<<<16, 256, 0, stream>>>(xsf, lin1_w, lin1_b, lin2_w, lin2_b, out);
}